// Round 2
// baseline (1434.618 us; speedup 1.0000x reference)
//
#include <hip/hip_runtime.h>
#include <hip/hip_bf16.h>

#define K_N_ATOMS 100000
#define K_N_EDGES 400000
#define K_N_MOLS  4000

typedef __attribute__((ext_vector_type(8))) short bf16x8;
typedef __attribute__((ext_vector_type(4))) float f32x4;

__device__ __forceinline__ unsigned short f2bf(float x) {
  union { __hip_bfloat16 b; unsigned short u; } c;
  c.b = __float2bfloat16(x);
  return c.u;
}

__device__ __forceinline__ unsigned pk2(float a, float b) {
  union { __hip_bfloat162 h; unsigned u; } c;
  c.h = __float22bfloat162_rn(make_float2(a, b));
  return c.u;
}

__device__ __forceinline__ bf16x8 pack8(float4 x, float4 y) {
  union { bf16x8 v; unsigned u[4]; } r;
  r.u[0] = pk2(x.x, x.y); r.u[1] = pk2(x.z, x.w);
  r.u[2] = pk2(y.x, y.y); r.u[3] = pk2(y.z, y.w);
  return r.v;
}

// Stage W (f32 row-major [KDIM][JDIM]) into A-fragment-linear bf16 LDS:
// A = W^T tile: lane l of frag (jt,ks) holds W[ks*32 + (l>>4)*8 + i][jt*16 + (l&15)]
template<int KDIM, int JDIM>
__device__ void stage_w(const float* __restrict__ W, unsigned short* frag, int tid) {
  for (int flat = tid * 4; flat < KDIM * JDIM; flat += 256 * 4) {
    int k = flat / JDIM;
    int j = flat - k * JDIM;
    float4 w4 = *(const float4*)(W + flat);
    float wv[4] = {w4.x, w4.y, w4.z, w4.w};
    int ks = k >> 5, kr = (k >> 3) & 3, i = k & 7;
#pragma unroll
    for (int c = 0; c < 4; ++c) {
      int jj = j + c;
      int jt = jj >> 4, ln = (jj & 15) + 16 * kr;
      frag[((jt * (KDIM / 32) + ks) * 64 + ln) * 8 + i] = f2bf(wv[c]);
    }
  }
}

// One 128-out layer: acc = bias; 8 j-tiles x 4 k-steps MFMA; relu; pack to h LDS [e][136]
__device__ __forceinline__ void mlp128_layer(
    const unsigned short* wfrag, const float* bias,
    bf16x8 (&bfr)[4][4], unsigned short* hbuf,
    int wave, int lo, int hi, int lane)
{
  for (int jt = 0; jt < 8; ++jt) {
    f32x4 bias_v = *(const f32x4*)(bias + jt * 16 + hi * 4);
    f32x4 acc0 = bias_v, acc1 = bias_v, acc2 = bias_v, acc3 = bias_v;
#pragma unroll
    for (int ks = 0; ks < 4; ++ks) {
      bf16x8 a = *(const bf16x8*)(wfrag + ((jt * 4 + ks) * 64 + lane) * 8);
      acc0 = __builtin_amdgcn_mfma_f32_16x16x32_bf16(a, bfr[0][ks], acc0, 0, 0, 0);
      acc1 = __builtin_amdgcn_mfma_f32_16x16x32_bf16(a, bfr[1][ks], acc1, 0, 0, 0);
      acc2 = __builtin_amdgcn_mfma_f32_16x16x32_bf16(a, bfr[2][ks], acc2, 0, 0, 0);
      acc3 = __builtin_amdgcn_mfma_f32_16x16x32_bf16(a, bfr[3][ks], acc3, 0, 0, 0);
    }
    f32x4 accs[4] = {acc0, acc1, acc2, acc3};
#pragma unroll
    for (int et = 0; et < 4; ++et) {
      int e = wave * 64 + et * 16 + lo;
      float v0 = fmaxf(accs[et][0], 0.f), v1 = fmaxf(accs[et][1], 0.f);
      float v2 = fmaxf(accs[et][2], 0.f), v3 = fmaxf(accs[et][3], 0.f);
      *(uint2*)(hbuf + e * 136 + jt * 16 + hi * 4) = make_uint2(pk2(v0, v1), pk2(v2, v3));
    }
  }
}

__device__ __forceinline__ void load_bfr(const unsigned short* hbuf, bf16x8 (&bfr)[4][4],
                                         int wave, int lo, int hi) {
#pragma unroll
  for (int et = 0; et < 4; ++et)
#pragma unroll
    for (int ks = 0; ks < 4; ++ks)
      bfr[et][ks] = *(const bf16x8*)(hbuf + (wave * 64 + et * 16 + lo) * 136 + ks * 32 + hi * 8);
}

// LDS: w1 32KB + w2 32KB + w3 16KB + biases 1.25KB + h 69.6KB = 152832 B
#define EDGE_SMEM (32768 + 32768 + 16384 + 512 + 512 + 256 + 69632)

__global__ __launch_bounds__(256, 1) void edge_mlp(
    const float* __restrict__ st_in, float* __restrict__ st_out,
    const int* __restrict__ esrc, const int* __restrict__ edst,
    const float* __restrict__ Win, const float* __restrict__ bin,
    const float* __restrict__ Wh, const float* __restrict__ bh,
    const float* __restrict__ Wout, const float* __restrict__ bout)
{
  extern __shared__ char smem[];
  unsigned short* w1 = (unsigned short*)smem;
  unsigned short* w2 = w1 + 16384;
  unsigned short* w3 = w2 + 16384;
  float* b1 = (float*)(w3 + 8192);
  float* b2 = b1 + 128;
  float* b3 = b2 + 128;
  unsigned short* hbuf = (unsigned short*)(b3 + 64);  // [256][136] bf16

  const int tid = threadIdx.x;
  stage_w<128, 128>(Win, w1, tid);
  stage_w<128, 128>(Wh, w2, tid);
  stage_w<128, 64>(Wout, w3, tid);
  if (tid < 128) { b1[tid] = bin[tid]; b2[tid] = bh[tid]; }
  else if (tid < 192) b3[tid - 128] = bout[tid - 128];
  __syncthreads();

  const int wave = tid >> 6, lane = tid & 63, lo = lane & 15, hi = lane >> 4;
  const int ebase = blockIdx.x * 256 + wave * 64;

  int srcs[4], dsts[4];
  unsigned vmask = 0;
#pragma unroll
  for (int et = 0; et < 4; ++et) {
    int e = ebase + et * 16 + lo;
    if (e < K_N_EDGES) vmask |= 1u << et;
    int ec = (e < K_N_EDGES) ? e : (K_N_EDGES - 1);
    srcs[et] = esrc[ec];
    dsts[et] = edst[ec];
  }

  // layer-1 B-fragments straight from global states (f32 -> bf16)
  bf16x8 bfr[4][4];
#pragma unroll
  for (int et = 0; et < 4; ++et) {
#pragma unroll
    for (int ks = 0; ks < 4; ++ks) {
      const float* base = (ks < 2)
          ? st_in + (size_t)srcs[et] * 64 + ks * 32 + hi * 8
          : st_in + (size_t)dsts[et] * 64 + (ks - 2) * 32 + hi * 8;
      float4 x = *(const float4*)base;
      float4 y = *(const float4*)(base + 4);
      bfr[et][ks] = pack8(x, y);
    }
  }

  mlp128_layer(w1, b1, bfr, hbuf, wave, lo, hi, lane);
  load_bfr(hbuf, bfr, wave, lo, hi);
  mlp128_layer(w2, b2, bfr, hbuf, wave, lo, hi, lane);
  load_bfr(hbuf, bfr, wave, lo, hi);

  // layer 3: 64 outputs, relu, atomic scatter to st_out[src]
  for (int jt = 0; jt < 4; ++jt) {
    f32x4 bias_v = *(const f32x4*)(b3 + jt * 16 + hi * 4);
    f32x4 acc0 = bias_v, acc1 = bias_v, acc2 = bias_v, acc3 = bias_v;
#pragma unroll
    for (int ks = 0; ks < 4; ++ks) {
      bf16x8 a = *(const bf16x8*)(w3 + ((jt * 4 + ks) * 64 + lane) * 8);
      acc0 = __builtin_amdgcn_mfma_f32_16x16x32_bf16(a, bfr[0][ks], acc0, 0, 0, 0);
      acc1 = __builtin_amdgcn_mfma_f32_16x16x32_bf16(a, bfr[1][ks], acc1, 0, 0, 0);
      acc2 = __builtin_amdgcn_mfma_f32_16x16x32_bf16(a, bfr[2][ks], acc2, 0, 0, 0);
      acc3 = __builtin_amdgcn_mfma_f32_16x16x32_bf16(a, bfr[3][ks], acc3, 0, 0, 0);
    }
    f32x4 accs[4] = {acc0, acc1, acc2, acc3};
#pragma unroll
    for (int et = 0; et < 4; ++et) {
      if (vmask & (1u << et)) {
        float* p = st_out + (size_t)srcs[et] * 64 + jt * 16 + hi * 4;
        unsafeAtomicAdd(p + 0, fmaxf(accs[et][0], 0.f));
        unsafeAtomicAdd(p + 1, fmaxf(accs[et][1], 0.f));
        unsafeAtomicAdd(p + 2, fmaxf(accs[et][2], 0.f));
        unsafeAtomicAdd(p + 3, fmaxf(accs[et][3], 0.f));
      }
    }
  }
}

__global__ void seg_sum(const float* __restrict__ st, const int* __restrict__ mol_ids,
                        float* __restrict__ mol) {
  int t = blockIdx.x * 256 + threadIdx.x;
  int atom = t >> 4, jq = (t & 15) * 4;
  if (atom >= K_N_ATOMS) return;
  float4 v = *(const float4*)(st + (size_t)atom * 64 + jq);
  int m = mol_ids[atom];
  float* p = mol + (size_t)m * 64 + jq;
  unsafeAtomicAdd(p + 0, v.x);
  unsafeAtomicAdd(p + 1, v.y);
  unsafeAtomicAdd(p + 2, v.z);
  unsafeAtomicAdd(p + 3, v.w);
}

// out[m][j] = relu(in[m][:] @ W[:, j] + bias[j]); 16 mols per block, j = thread
template<int KDIM>
__global__ void mlp_layer(const float* __restrict__ in, const float* __restrict__ W,
                          const float* __restrict__ bias, float* __restrict__ out) {
  __shared__ float in_l[16][KDIM + 4];
  int m0 = blockIdx.x * 16;
  int t = threadIdx.x;
  for (int flat = t; flat < 16 * KDIM; flat += 256) {
    int m = flat / KDIM, k = flat - m * KDIM;
    in_l[m][k] = in[(size_t)(m0 + m) * KDIM + k];
  }
  __syncthreads();
  int j = t;
  float b = bias[j];
  float acc[16];
#pragma unroll
  for (int m = 0; m < 16; ++m) acc[m] = b;
  for (int k = 0; k < KDIM; ++k) {
    float w = W[(size_t)k * 256 + j];
#pragma unroll
    for (int m = 0; m < 16; ++m) acc[m] += in_l[m][k] * w;
  }
#pragma unroll
  for (int m = 0; m < 16; ++m)
    out[(size_t)(m0 + m) * 256 + j] = fmaxf(acc[m], 0.f);
}

// final 256 -> 1: one wave per molecule
__global__ void mlp_out_k(const float* __restrict__ in, const float* __restrict__ W,
                          const float* __restrict__ bias, float* __restrict__ out) {
  int wave = threadIdx.x >> 6, lane = threadIdx.x & 63;
  int m = blockIdx.x * 4 + wave;
  if (m >= K_N_MOLS) return;
  float4 v = *(const float4*)(in + (size_t)m * 256 + lane * 4);
  float4 w = *(const float4*)(W + lane * 4);
  float s = v.x * w.x + v.y * w.y + v.z * w.z + v.w * w.w;
  for (int off = 32; off; off >>= 1) s += __shfl_down(s, off);
  if (lane == 0) out[m] = s + bias[0];
}

extern "C" void kernel_launch(void* const* d_in, const int* in_sizes, int n_in,
                              void* d_out, int out_size, void* d_ws, size_t ws_size,
                              hipStream_t stream) {
  const float* atom_states = (const float*)d_in[0];
  const int* esrc = (const int*)d_in[1];
  const int* edst = (const int*)d_in[2];
  const int* mol_ids = (const int*)d_in[3];
  const float* msWin = (const float*)d_in[4];
  const float* msbin = (const float*)d_in[5];
  const float* msWh = (const float*)d_in[6];
  const float* msbh = (const float*)d_in[7];
  const float* msWout = (const float*)d_in[8];
  const float* msbout = (const float*)d_in[9];
  const float* roWin = (const float*)d_in[10];
  const float* robin = (const float*)d_in[11];
  const float* roWh = (const float*)d_in[12];
  const float* robh = (const float*)d_in[13];
  const float* roWout = (const float*)d_in[14];
  const float* robout = (const float*)d_in[15];
  float* out = (float*)d_out;

  float* sA = (float*)d_ws;                       // 100000*64
  float* sB = sA + (size_t)K_N_ATOMS * 64;        // 100000*64
  float* mol = sB + (size_t)K_N_ATOMS * 64;       // 4000*64
  float* r1 = mol + (size_t)K_N_MOLS * 64;        // 4000*256
  float* r2 = r1 + (size_t)K_N_MOLS * 256;        // 4000*256

  hipFuncSetAttribute((const void*)edge_mlp,
                      hipFuncAttributeMaxDynamicSharedMemorySize, EDGE_SMEM);

  const int EG = (K_N_EDGES + 255) / 256;  // 1563
  const size_t stBytes = (size_t)K_N_ATOMS * 64 * sizeof(float);

  // step 0: atom_states -> sA
  hipMemsetAsync(sA, 0, stBytes, stream);
  edge_mlp<<<EG, 256, EDGE_SMEM, stream>>>(
      atom_states, sA, esrc, edst,
      msWin, msbin, msWh, msbh, msWout, msbout);
  // step 1: sA -> sB
  hipMemsetAsync(sB, 0, stBytes, stream);
  edge_mlp<<<EG, 256, EDGE_SMEM, stream>>>(
      sA, sB, esrc, edst,
      msWin + 128 * 128, msbin + 128, msWh + 128 * 128, msbh + 128,
      msWout + 128 * 64, msbout + 64);
  // step 2: sB -> sA
  hipMemsetAsync(sA, 0, stBytes, stream);
  edge_mlp<<<EG, 256, EDGE_SMEM, stream>>>(
      sB, sA, esrc, edst,
      msWin + 2 * 128 * 128, msbin + 2 * 128, msWh + 2 * 128 * 128, msbh + 2 * 128,
      msWout + 2 * 128 * 64, msbout + 2 * 64);

  // readout
  hipMemsetAsync(mol, 0, (size_t)K_N_MOLS * 64 * sizeof(float), stream);
  seg_sum<<<(K_N_ATOMS * 16) / 256, 256, 0, stream>>>(sA, mol_ids, mol);
  mlp_layer<64><<<K_N_MOLS / 16, 256, 0, stream>>>(mol, roWin, robin, r1);
  mlp_layer<256><<<K_N_MOLS / 16, 256, 0, stream>>>(r1, roWh, robh, r2);
  mlp_layer<256><<<K_N_MOLS / 16, 256, 0, stream>>>(r2, roWh + 256 * 256, robh + 256, r1);
  mlp_out_k<<<K_N_MOLS / 4, 256, 0, stream>>>(r1, roWout, robout, out);
}

// Round 3
// 1234.105 us; speedup vs baseline: 1.1625x; 1.1625x over previous
//
#include <hip/hip_runtime.h>
#include <hip/hip_bf16.h>

#define K_N_ATOMS 100000
#define K_N_EDGES 400000
#define K_N_MOLS  4000

typedef __attribute__((ext_vector_type(8))) short bf16x8;
typedef __attribute__((ext_vector_type(4))) float f32x4;

__device__ __forceinline__ unsigned short f2bf(float x) {
  union { __hip_bfloat16 b; unsigned short u; } c;
  c.b = __float2bfloat16(x);
  return c.u;
}

__device__ __forceinline__ unsigned pk2(float a, float b) {
  union { __hip_bfloat162 h; unsigned u; } c;
  c.h = __float22bfloat162_rn(make_float2(a, b));
  return c.u;
}

__device__ __forceinline__ bf16x8 pack8(float4 x, float4 y) {
  union { bf16x8 v; unsigned u[4]; } r;
  r.u[0] = pk2(x.x, x.y); r.u[1] = pk2(x.z, x.w);
  r.u[2] = pk2(y.x, y.y); r.u[3] = pk2(y.z, y.w);
  return r.v;
}

// ---- weight prep: f32 row-major [128][J] -> bf16 A-fragment-linear global ----
// frag layout: [(jt*4+ks)*64 + ln]*8 + i  holds W[ks*32 + (ln>>4)*8 + i][jt*16 + (ln&15)]
__global__ void prep_w(const float* __restrict__ Win, const float* __restrict__ Wh,
                       const float* __restrict__ Wout, unsigned short* __restrict__ wf) {
  int s = blockIdx.y;
  int flat = (blockIdx.x * 256 + threadIdx.x) * 4;  // 40960 elems, grid.x = 40
  const float* W; unsigned short* dst; int jbits, local;
  if (flat < 16384)      { W = Win + s * 16384; dst = wf + s * 40960;         local = flat;         jbits = 7; }
  else if (flat < 32768) { W = Wh  + s * 16384; dst = wf + s * 40960 + 16384; local = flat - 16384; jbits = 7; }
  else                   { W = Wout+ s * 8192;  dst = wf + s * 40960 + 32768; local = flat - 32768; jbits = 6; }
  int k = local >> jbits, j = local & ((1 << jbits) - 1);
  float4 w4 = *(const float4*)(W + local);
  float wv[4] = {w4.x, w4.y, w4.z, w4.w};
  int ks = k >> 5, kr = (k >> 3) & 3, i = k & 7;
#pragma unroll
  for (int c = 0; c < 4; ++c) {
    int jj = j + c;
    int jt = jj >> 4, ln = (jj & 15) + 16 * kr;
    dst[((jt * 4 + ks) * 64 + ln) * 8 + i] = f2bf(wv[c]);
  }
}

// ---- f32 states -> bf16 mirror ----
__global__ void st2bf(const float* __restrict__ in, unsigned short* __restrict__ out, int n8) {
  int t = blockIdx.x * 256 + threadIdx.x;
  if (t >= n8) return;
  float4 x = ((const float4*)in)[t * 2];
  float4 y = ((const float4*)in)[t * 2 + 1];
  ((bf16x8*)out)[t] = pack8(x, y);
}

__device__ __forceinline__ float relu(float x) { return fmaxf(x, 0.f); }

// 128->128 layer: bfr (B-frags) in, packed bf16 outputs p[et][jt][2] out
__device__ __forceinline__ void layer128(const unsigned short* __restrict__ wf,
                                         const float* __restrict__ bias,
                                         bf16x8 (&bfr)[4][4], unsigned (&p)[4][8][2],
                                         int lane, int h) {
#pragma unroll
  for (int jt = 0; jt < 8; ++jt) {
    f32x4 bv = *(const f32x4*)(bias + jt * 16 + h * 4);
    f32x4 a0 = bv, a1 = bv, a2 = bv, a3 = bv;
#pragma unroll
    for (int ks = 0; ks < 4; ++ks) {
      bf16x8 a = *(const bf16x8*)(wf + ((jt * 4 + ks) * 64 + lane) * 8);
      a0 = __builtin_amdgcn_mfma_f32_16x16x32_bf16(a, bfr[0][ks], a0, 0, 0, 0);
      a1 = __builtin_amdgcn_mfma_f32_16x16x32_bf16(a, bfr[1][ks], a1, 0, 0, 0);
      a2 = __builtin_amdgcn_mfma_f32_16x16x32_bf16(a, bfr[2][ks], a2, 0, 0, 0);
      a3 = __builtin_amdgcn_mfma_f32_16x16x32_bf16(a, bfr[3][ks], a3, 0, 0, 0);
    }
    p[0][jt][0] = pk2(relu(a0[0]), relu(a0[1])); p[0][jt][1] = pk2(relu(a0[2]), relu(a0[3]));
    p[1][jt][0] = pk2(relu(a1[0]), relu(a1[1])); p[1][jt][1] = pk2(relu(a1[2]), relu(a1[3]));
    p[2][jt][0] = pk2(relu(a2[0]), relu(a2[1])); p[2][jt][1] = pk2(relu(a2[2]), relu(a2[3]));
    p[3][jt][0] = pk2(relu(a3[0]), relu(a3[1])); p[3][jt][1] = pk2(relu(a3[2]), relu(a3[3]));
  }
}

// D-layout -> B-fragment layout, in-register via shfl among lanes {lo,lo+16,lo+32,lo+48}
__device__ __forceinline__ void transpose_p(const unsigned (&p)[4][8][2], bf16x8 (&bfr)[4][4],
                                            int lo, int h) {
  const int hsel = (h & 1) * 2;
#pragma unroll
  for (int et = 0; et < 4; ++et) {
#pragma unroll
    for (int ks = 0; ks < 4; ++ks) {
      union { unsigned u[4]; bf16x8 v; } cv;
#pragma unroll
      for (int w = 0; w < 4; ++w) {
        int srcLane = lo + 16 * (hsel + (w >> 1));
        unsigned d0 = (unsigned)__shfl((int)p[et][2 * ks][w & 1], srcLane, 64);
        unsigned d1 = (unsigned)__shfl((int)p[et][2 * ks + 1][w & 1], srcLane, 64);
        cv.u[w] = (h < 2) ? d0 : d1;
      }
      bfr[et][ks] = cv.v;
    }
  }
}

__global__ __launch_bounds__(256, 3) void edge_mlp2(
    const unsigned short* __restrict__ stb, float* __restrict__ st_out,
    const int* __restrict__ esrc, const int* __restrict__ edst,
    const unsigned short* __restrict__ wf,
    const float* __restrict__ b1, const float* __restrict__ b2, const float* __restrict__ b3) {
  const int tid = threadIdx.x;
  const int wave = tid >> 6, lane = tid & 63, lo = lane & 15, h = lane >> 4;
  const int ebase = blockIdx.x * 256 + wave * 64;

  int srcs[4], dsts[4];
  unsigned vmask = 0;
#pragma unroll
  for (int et = 0; et < 4; ++et) {
    int e = ebase + et * 16 + lo;
    if (e < K_N_EDGES) vmask |= 1u << et;
    int ec = (e < K_N_EDGES) ? e : (K_N_EDGES - 1);
    srcs[et] = esrc[ec];
    dsts[et] = edst[ec];
  }

  // layer-1 B-frags: direct bf16 gather. lane needs act[e][k = ks*32 + h*8 + i]
  bf16x8 bfr[4][4];
#pragma unroll
  for (int et = 0; et < 4; ++et) {
    const unsigned short* rs = stb + (size_t)srcs[et] * 64 + h * 8;
    const unsigned short* rd = stb + (size_t)dsts[et] * 64 + h * 8;
    bfr[et][0] = *(const bf16x8*)(rs);
    bfr[et][1] = *(const bf16x8*)(rs + 32);
    bfr[et][2] = *(const bf16x8*)(rd);
    bfr[et][3] = *(const bf16x8*)(rd + 32);
  }

  const unsigned short* w1 = wf;
  const unsigned short* w2 = wf + 16384;
  const unsigned short* w3 = wf + 32768;

  unsigned p[4][8][2];
  layer128(w1, b1, bfr, p, lane, h);
  transpose_p(p, bfr, lo, h);
  layer128(w2, b2, bfr, p, lane, h);
  transpose_p(p, bfr, lo, h);

  // layer 3: 128->64, relu, atomic scatter
#pragma unroll
  for (int jt = 0; jt < 4; ++jt) {
    f32x4 bv = *(const f32x4*)(b3 + jt * 16 + h * 4);
    f32x4 a0 = bv, a1 = bv, a2 = bv, a3 = bv;
#pragma unroll
    for (int ks = 0; ks < 4; ++ks) {
      bf16x8 a = *(const bf16x8*)(w3 + ((jt * 4 + ks) * 64 + lane) * 8);
      a0 = __builtin_amdgcn_mfma_f32_16x16x32_bf16(a, bfr[0][ks], a0, 0, 0, 0);
      a1 = __builtin_amdgcn_mfma_f32_16x16x32_bf16(a, bfr[1][ks], a1, 0, 0, 0);
      a2 = __builtin_amdgcn_mfma_f32_16x16x32_bf16(a, bfr[2][ks], a2, 0, 0, 0);
      a3 = __builtin_amdgcn_mfma_f32_16x16x32_bf16(a, bfr[3][ks], a3, 0, 0, 0);
    }
    f32x4 accs[4] = {a0, a1, a2, a3};
#pragma unroll
    for (int et = 0; et < 4; ++et) {
      if (vmask & (1u << et)) {
        float* ptr = st_out + (size_t)srcs[et] * 64 + jt * 16 + h * 4;
        unsafeAtomicAdd(ptr + 0, relu(accs[et][0]));
        unsafeAtomicAdd(ptr + 1, relu(accs[et][1]));
        unsafeAtomicAdd(ptr + 2, relu(accs[et][2]));
        unsafeAtomicAdd(ptr + 3, relu(accs[et][3]));
      }
    }
  }
}

// ---- readout (mol_ids is sorted -> contiguous segments, no atomics) ----
__global__ void mol_bounds(const int* __restrict__ mol_ids, int* __restrict__ start) {
  int a = blockIdx.x * 256 + threadIdx.x;
  if (a >= K_N_ATOMS) return;
  int id = mol_ids[a];
  int prev = (a == 0) ? -1 : mol_ids[a - 1];
  for (int m = prev + 1; m <= id; ++m) start[m] = a;
  if (a == K_N_ATOMS - 1)
    for (int m = id + 1; m <= K_N_MOLS; ++m) start[m] = K_N_ATOMS;
}

__global__ void mol_sum(const float* __restrict__ st, const int* __restrict__ start,
                        float* __restrict__ mol) {
  int wv = (blockIdx.x * 256 + threadIdx.x) >> 6;
  int lane = threadIdx.x & 63;
  if (wv >= K_N_MOLS) return;
  int s = start[wv], e = start[wv + 1];
  float acc = 0.f;
  for (int a = s; a < e; ++a) acc += st[(size_t)a * 64 + lane];
  mol[(size_t)wv * 64 + lane] = acc;
}

// out[m][j] = relu(in[m][:] @ W[:, j] + bias[j]); 16 mols per block, j = thread
template<int KDIM>
__global__ void mlp_layer(const float* __restrict__ in, const float* __restrict__ W,
                          const float* __restrict__ bias, float* __restrict__ out) {
  __shared__ float in_l[16][KDIM + 4];
  int m0 = blockIdx.x * 16;
  int t = threadIdx.x;
  for (int flat = t; flat < 16 * KDIM; flat += 256) {
    int m = flat / KDIM, k = flat - m * KDIM;
    in_l[m][k] = in[(size_t)(m0 + m) * KDIM + k];
  }
  __syncthreads();
  int j = t;
  float b = bias[j];
  float acc[16];
#pragma unroll
  for (int m = 0; m < 16; ++m) acc[m] = b;
  for (int k = 0; k < KDIM; ++k) {
    float w = W[(size_t)k * 256 + j];
#pragma unroll
    for (int m = 0; m < 16; ++m) acc[m] += in_l[m][k] * w;
  }
#pragma unroll
  for (int m = 0; m < 16; ++m)
    out[(size_t)(m0 + m) * 256 + j] = fmaxf(acc[m], 0.f);
}

__global__ void mlp_out_k(const float* __restrict__ in, const float* __restrict__ W,
                          const float* __restrict__ bias, float* __restrict__ out) {
  int wave = threadIdx.x >> 6, lane = threadIdx.x & 63;
  int m = blockIdx.x * 4 + wave;
  if (m >= K_N_MOLS) return;
  float4 v = *(const float4*)(in + (size_t)m * 256 + lane * 4);
  float4 w = *(const float4*)(W + lane * 4);
  float s = v.x * w.x + v.y * w.y + v.z * w.z + v.w * w.w;
  for (int off = 32; off; off >>= 1) s += __shfl_down(s, off);
  if (lane == 0) out[m] = s + bias[0];
}

extern "C" void kernel_launch(void* const* d_in, const int* in_sizes, int n_in,
                              void* d_out, int out_size, void* d_ws, size_t ws_size,
                              hipStream_t stream) {
  const float* atom_states = (const float*)d_in[0];
  const int* esrc = (const int*)d_in[1];
  const int* edst = (const int*)d_in[2];
  const int* mol_ids = (const int*)d_in[3];
  const float* msWin = (const float*)d_in[4];
  const float* msbin = (const float*)d_in[5];
  const float* msWh = (const float*)d_in[6];
  const float* msbh = (const float*)d_in[7];
  const float* msWout = (const float*)d_in[8];
  const float* msbout = (const float*)d_in[9];
  const float* roWin = (const float*)d_in[10];
  const float* robin = (const float*)d_in[11];
  const float* roWh = (const float*)d_in[12];
  const float* robh = (const float*)d_in[13];
  const float* roWout = (const float*)d_in[14];
  const float* robout = (const float*)d_in[15];
  float* out = (float*)d_out;

  // workspace carve-out
  float* sA = (float*)d_ws;                               // 6.4M f32
  float* sB = sA + (size_t)K_N_ATOMS * 64;                // 6.4M f32
  unsigned short* bA = (unsigned short*)(sB + (size_t)K_N_ATOMS * 64);  // 6.4M bf16
  unsigned short* bB = bA + (size_t)K_N_ATOMS * 64;       // 6.4M bf16
  unsigned short* wfb = bB + (size_t)K_N_ATOMS * 64;      // 3*40960 bf16
  float* mol = (float*)(wfb + 3 * 40960);                 // 4000*64
  float* r1 = mol + (size_t)K_N_MOLS * 64;                // 4000*256
  float* r2 = r1 + (size_t)K_N_MOLS * 256;                // 4000*256
  int* mstart = (int*)(r2 + (size_t)K_N_MOLS * 256);      // 4001 ints

  const int EG = (K_N_EDGES + 255) / 256;  // 1563
  const size_t stBytes = (size_t)K_N_ATOMS * 64 * sizeof(float);
  const int N8 = K_N_ATOMS * 64 / 8;  // 800000

  prep_w<<<dim3(40, 3), 256, 0, stream>>>(msWin, msWh, msWout, wfb);

  // step 0
  st2bf<<<(N8 + 255) / 256, 256, 0, stream>>>(atom_states, bA, N8);
  hipMemsetAsync(sA, 0, stBytes, stream);
  edge_mlp2<<<EG, 256, 0, stream>>>(bA, sA, esrc, edst, wfb,
                                    msbin, msbh, msbout);
  // step 1
  st2bf<<<(N8 + 255) / 256, 256, 0, stream>>>(sA, bB, N8);
  hipMemsetAsync(sB, 0, stBytes, stream);
  edge_mlp2<<<EG, 256, 0, stream>>>(bB, sB, esrc, edst, wfb + 40960,
                                    msbin + 128, msbh + 128, msbout + 64);
  // step 2
  st2bf<<<(N8 + 255) / 256, 256, 0, stream>>>(sB, bA, N8);
  hipMemsetAsync(sA, 0, stBytes, stream);
  edge_mlp2<<<EG, 256, 0, stream>>>(bA, sA, esrc, edst, wfb + 2 * 40960,
                                    msbin + 2 * 128, msbh + 2 * 128, msbout + 2 * 64);

  // readout
  mol_bounds<<<(K_N_ATOMS + 255) / 256, 256, 0, stream>>>(mol_ids, mstart);
  mol_sum<<<K_N_MOLS / 4, 256, 0, stream>>>(sA, mstart, mol);
  mlp_layer<64><<<K_N_MOLS / 16, 256, 0, stream>>>(mol, roWin, robin, r1);
  mlp_layer<256><<<K_N_MOLS / 16, 256, 0, stream>>>(r1, roWh, robh, r2);
  mlp_layer<256><<<K_N_MOLS / 16, 256, 0, stream>>>(r2, roWh + 256 * 256, robh + 256, r1);
  mlp_out_k<<<K_N_MOLS / 4, 256, 0, stream>>>(r1, roWout, robout, out);
}

// Round 4
// 538.389 us; speedup vs baseline: 2.6646x; 2.2922x over previous
//
#include <hip/hip_runtime.h>
#include <hip/hip_bf16.h>

#define K_N_ATOMS 100000
#define K_N_EDGES 400000
#define K_N_MOLS  4000

typedef __attribute__((ext_vector_type(8))) short bf16x8;
typedef __attribute__((ext_vector_type(4))) float f32x4;

__device__ __forceinline__ unsigned short f2bf(float x) {
  union { __hip_bfloat16 b; unsigned short u; } c;
  c.b = __float2bfloat16(x);
  return c.u;
}

__device__ __forceinline__ unsigned pk2(float a, float b) {
  union { __hip_bfloat162 h; unsigned u; } c;
  c.h = __float22bfloat162_rn(make_float2(a, b));
  return c.u;
}

__device__ __forceinline__ bf16x8 pack8(float4 x, float4 y) {
  union { bf16x8 v; unsigned u[4]; } r;
  r.u[0] = pk2(x.x, x.y); r.u[1] = pk2(x.z, x.w);
  r.u[2] = pk2(y.x, y.y); r.u[3] = pk2(y.z, y.w);
  return r.v;
}

__device__ __forceinline__ float relu(float x) { return fmaxf(x, 0.f); }

// ---- weight prep: f32 row-major [128][J] -> bf16 A-fragment-linear global ----
__global__ void prep_w(const float* __restrict__ Win, const float* __restrict__ Wh,
                       const float* __restrict__ Wout, unsigned short* __restrict__ wf) {
  int s = blockIdx.y;
  int flat = (blockIdx.x * 256 + threadIdx.x) * 4;  // 40960 elems, grid.x = 40
  const float* W; unsigned short* dst; int jbits, local;
  if (flat < 16384)      { W = Win + s * 16384; dst = wf + s * 40960;         local = flat;         jbits = 7; }
  else if (flat < 32768) { W = Wh  + s * 16384; dst = wf + s * 40960 + 16384; local = flat - 16384; jbits = 7; }
  else                   { W = Wout+ s * 8192;  dst = wf + s * 40960 + 32768; local = flat - 32768; jbits = 6; }
  int k = local >> jbits, j = local & ((1 << jbits) - 1);
  float4 w4 = *(const float4*)(W + local);
  float wv[4] = {w4.x, w4.y, w4.z, w4.w};
  int ks = k >> 5, kr = (k >> 3) & 3, i = k & 7;
#pragma unroll
  for (int c = 0; c < 4; ++c) {
    int jj = j + c;
    int jt = jj >> 4, ln = (jj & 15) + 16 * kr;
    dst[((jt * 4 + ks) * 64 + ln) * 8 + i] = f2bf(wv[c]);
  }
}

// ---- f32 states -> bf16 mirror (input only) ----
__global__ void st2bf(const float* __restrict__ in, unsigned short* __restrict__ out, int n8) {
  int t = blockIdx.x * 256 + threadIdx.x;
  if (t >= n8) return;
  float4 x = ((const float4*)in)[t * 2];
  float4 y = ((const float4*)in)[t * 2 + 1];
  ((bf16x8*)out)[t] = pack8(x, y);
}

// ---- counting sort of edges by src ----
__global__ void k_hist(const int* __restrict__ esrc, int* __restrict__ cnt) {
  int t = blockIdx.x * 256 + threadIdx.x;
  if (t < K_N_EDGES) atomicAdd(&cnt[esrc[t]], 1);
}

__global__ void k_blocksum(const int* __restrict__ cnt, int* __restrict__ partial) {
  __shared__ int red[256];
  int i = blockIdx.x * 256 + threadIdx.x;
  red[threadIdx.x] = (i < K_N_ATOMS) ? cnt[i] : 0;
  __syncthreads();
  for (int off = 128; off; off >>= 1) {
    if (threadIdx.x < off) red[threadIdx.x] += red[threadIdx.x + off];
    __syncthreads();
  }
  if (!threadIdx.x) partial[blockIdx.x] = red[0];
}

__global__ void k_scanpart(int* __restrict__ partial, int nb) {
  if (threadIdx.x == 0 && blockIdx.x == 0) {
    int acc = 0;
    for (int b = 0; b < nb; ++b) { int t = partial[b]; partial[b] = acc; acc += t; }
  }
}

__global__ void k_scanfinal(const int* __restrict__ cnt, const int* __restrict__ poffs,
                            int* __restrict__ start, int* __restrict__ cur) {
  __shared__ int sh[256];
  int tid = threadIdx.x;
  int i = blockIdx.x * 256 + tid;
  int v = (i < K_N_ATOMS) ? cnt[i] : 0;
  sh[tid] = v;
  __syncthreads();
  for (int off = 1; off < 256; off <<= 1) {
    int t = (tid >= off) ? sh[tid - off] : 0;
    __syncthreads();
    sh[tid] += t;
    __syncthreads();
  }
  int ex = sh[tid] - v + poffs[blockIdx.x];
  if (i < K_N_ATOMS) { start[i] = ex; cur[i] = ex; }
  if (i == K_N_ATOMS - 1) start[K_N_ATOMS] = ex + v;
}

__global__ void k_scatter(const int* __restrict__ esrc, const int* __restrict__ edst,
                          int* __restrict__ cur, int* __restrict__ es, int* __restrict__ ed) {
  int t = blockIdx.x * 256 + threadIdx.x;
  if (t < K_N_EDGES) {
    int s = esrc[t];
    int p = atomicAdd(&cur[s], 1);
    es[p] = s;
    ed[p] = edst[t];
  }
}

// ---- edge MLP (3 layers, MFMA), stores per-edge messages bf16, NO atomics ----
__device__ __forceinline__ void layer128(const unsigned short* __restrict__ wf,
                                         const float* __restrict__ bias,
                                         bf16x8 (&bfr)[4][4], unsigned (&p)[4][8][2],
                                         int lane, int h) {
#pragma unroll
  for (int jt = 0; jt < 8; ++jt) {
    f32x4 bv = *(const f32x4*)(bias + jt * 16 + h * 4);
    f32x4 a0 = bv, a1 = bv, a2 = bv, a3 = bv;
#pragma unroll
    for (int ks = 0; ks < 4; ++ks) {
      bf16x8 a = *(const bf16x8*)(wf + ((jt * 4 + ks) * 64 + lane) * 8);
      a0 = __builtin_amdgcn_mfma_f32_16x16x32_bf16(a, bfr[0][ks], a0, 0, 0, 0);
      a1 = __builtin_amdgcn_mfma_f32_16x16x32_bf16(a, bfr[1][ks], a1, 0, 0, 0);
      a2 = __builtin_amdgcn_mfma_f32_16x16x32_bf16(a, bfr[2][ks], a2, 0, 0, 0);
      a3 = __builtin_amdgcn_mfma_f32_16x16x32_bf16(a, bfr[3][ks], a3, 0, 0, 0);
    }
    p[0][jt][0] = pk2(relu(a0[0]), relu(a0[1])); p[0][jt][1] = pk2(relu(a0[2]), relu(a0[3]));
    p[1][jt][0] = pk2(relu(a1[0]), relu(a1[1])); p[1][jt][1] = pk2(relu(a1[2]), relu(a1[3]));
    p[2][jt][0] = pk2(relu(a2[0]), relu(a2[1])); p[2][jt][1] = pk2(relu(a2[2]), relu(a2[3]));
    p[3][jt][0] = pk2(relu(a3[0]), relu(a3[1])); p[3][jt][1] = pk2(relu(a3[2]), relu(a3[3]));
  }
}

__device__ __forceinline__ void transpose_p(const unsigned (&p)[4][8][2], bf16x8 (&bfr)[4][4],
                                            int lo, int h) {
  const int hsel = (h & 1) * 2;
#pragma unroll
  for (int et = 0; et < 4; ++et) {
#pragma unroll
    for (int ks = 0; ks < 4; ++ks) {
      union { unsigned u[4]; bf16x8 v; } cv;
#pragma unroll
      for (int w = 0; w < 4; ++w) {
        int srcLane = lo + 16 * (hsel + (w >> 1));
        unsigned d0 = (unsigned)__shfl((int)p[et][2 * ks][w & 1], srcLane, 64);
        unsigned d1 = (unsigned)__shfl((int)p[et][2 * ks + 1][w & 1], srcLane, 64);
        cv.u[w] = (h < 2) ? d0 : d1;
      }
      bfr[et][ks] = cv.v;
    }
  }
}

__global__ __launch_bounds__(256, 3) void edge_msg(
    const unsigned short* __restrict__ stb, unsigned short* __restrict__ m_buf,
    const int* __restrict__ es, const int* __restrict__ ed,
    const unsigned short* __restrict__ wf,
    const float* __restrict__ b1, const float* __restrict__ b2, const float* __restrict__ b3) {
  const int tid = threadIdx.x;
  const int wave = tid >> 6, lane = tid & 63, lo = lane & 15, h = lane >> 4;
  const int ebase = blockIdx.x * 256 + wave * 64;

  int srcs[4], dsts[4];
  unsigned vmask = 0;
#pragma unroll
  for (int et = 0; et < 4; ++et) {
    int e = ebase + et * 16 + lo;
    if (e < K_N_EDGES) vmask |= 1u << et;
    int ec = (e < K_N_EDGES) ? e : (K_N_EDGES - 1);
    srcs[et] = es[ec];
    dsts[et] = ed[ec];
  }

  // layer-1 B-frags: lane needs act[e][k = ks*32 + h*8 + i]
  bf16x8 bfr[4][4];
#pragma unroll
  for (int et = 0; et < 4; ++et) {
    const unsigned short* rs = stb + (size_t)srcs[et] * 64 + h * 8;
    const unsigned short* rd = stb + (size_t)dsts[et] * 64 + h * 8;
    bfr[et][0] = *(const bf16x8*)(rs);
    bfr[et][1] = *(const bf16x8*)(rs + 32);
    bfr[et][2] = *(const bf16x8*)(rd);
    bfr[et][3] = *(const bf16x8*)(rd + 32);
  }

  unsigned p[4][8][2];
  layer128(wf, b1, bfr, p, lane, h);
  transpose_p(p, bfr, lo, h);
  layer128(wf + 16384, b2, bfr, p, lane, h);
  transpose_p(p, bfr, lo, h);

  const unsigned short* w3 = wf + 32768;
#pragma unroll
  for (int jt = 0; jt < 4; ++jt) {
    f32x4 bv = *(const f32x4*)(b3 + jt * 16 + h * 4);
    f32x4 a0 = bv, a1 = bv, a2 = bv, a3 = bv;
#pragma unroll
    for (int ks = 0; ks < 4; ++ks) {
      bf16x8 a = *(const bf16x8*)(w3 + ((jt * 4 + ks) * 64 + lane) * 8);
      a0 = __builtin_amdgcn_mfma_f32_16x16x32_bf16(a, bfr[0][ks], a0, 0, 0, 0);
      a1 = __builtin_amdgcn_mfma_f32_16x16x32_bf16(a, bfr[1][ks], a1, 0, 0, 0);
      a2 = __builtin_amdgcn_mfma_f32_16x16x32_bf16(a, bfr[2][ks], a2, 0, 0, 0);
      a3 = __builtin_amdgcn_mfma_f32_16x16x32_bf16(a, bfr[3][ks], a3, 0, 0, 0);
    }
    f32x4 accs[4] = {a0, a1, a2, a3};
#pragma unroll
    for (int et = 0; et < 4; ++et) {
      if (vmask & (1u << et)) {
        int e = ebase + et * 16 + lo;
        *(uint2*)(m_buf + (size_t)e * 64 + jt * 16 + h * 4) =
            make_uint2(pk2(relu(accs[et][0]), relu(accs[et][1])),
                       pk2(relu(accs[et][2]), relu(accs[et][3])));
      }
    }
  }
}

// ---- segmented aggregation: one wave per atom, plain stores ----
__global__ __launch_bounds__(256) void seg_agg(
    const unsigned short* __restrict__ m_buf, const int* __restrict__ start,
    float* __restrict__ st_f32, unsigned short* __restrict__ stb_out) {
  int wv = (blockIdx.x * 256 + threadIdx.x) >> 6;
  int lane = threadIdx.x & 63;
  if (wv >= K_N_ATOMS) return;
  int s = start[wv], e = start[wv + 1];
  float acc = 0.f;
  int r = s;
  for (; r + 4 <= e; r += 4) {
    float v0 = __bfloat162float(*(const __hip_bfloat16*)(m_buf + (size_t)(r + 0) * 64 + lane));
    float v1 = __bfloat162float(*(const __hip_bfloat16*)(m_buf + (size_t)(r + 1) * 64 + lane));
    float v2 = __bfloat162float(*(const __hip_bfloat16*)(m_buf + (size_t)(r + 2) * 64 + lane));
    float v3 = __bfloat162float(*(const __hip_bfloat16*)(m_buf + (size_t)(r + 3) * 64 + lane));
    acc += (v0 + v1) + (v2 + v3);
  }
  for (; r < e; ++r)
    acc += __bfloat162float(*(const __hip_bfloat16*)(m_buf + (size_t)r * 64 + lane));
  st_f32[(size_t)wv * 64 + lane] = acc;
  stb_out[(size_t)wv * 64 + lane] = f2bf(acc);
}

// ---- readout ----
__global__ void mol_bounds(const int* __restrict__ mol_ids, int* __restrict__ start) {
  int a = blockIdx.x * 256 + threadIdx.x;
  if (a >= K_N_ATOMS) return;
  int id = mol_ids[a];
  int prev = (a == 0) ? -1 : mol_ids[a - 1];
  for (int m = prev + 1; m <= id; ++m) start[m] = a;
  if (a == K_N_ATOMS - 1)
    for (int m = id + 1; m <= K_N_MOLS; ++m) start[m] = K_N_ATOMS;
}

__global__ void mol_sum(const float* __restrict__ st, const int* __restrict__ start,
                        float* __restrict__ mol) {
  int wv = (blockIdx.x * 256 + threadIdx.x) >> 6;
  int lane = threadIdx.x & 63;
  if (wv >= K_N_MOLS) return;
  int s = start[wv], e = start[wv + 1];
  float acc = 0.f;
  for (int a = s; a < e; ++a) acc += st[(size_t)a * 64 + lane];
  mol[(size_t)wv * 64 + lane] = acc;
}

template<int KDIM>
__global__ void mlp_layer(const float* __restrict__ in, const float* __restrict__ W,
                          const float* __restrict__ bias, float* __restrict__ out) {
  __shared__ float in_l[16][KDIM + 4];
  int m0 = blockIdx.x * 16;
  int t = threadIdx.x;
  for (int flat = t; flat < 16 * KDIM; flat += 256) {
    int m = flat / KDIM, k = flat - m * KDIM;
    in_l[m][k] = in[(size_t)(m0 + m) * KDIM + k];
  }
  __syncthreads();
  int j = t;
  float b = bias[j];
  float acc[16];
#pragma unroll
  for (int m = 0; m < 16; ++m) acc[m] = b;
  for (int k = 0; k < KDIM; ++k) {
    float w = W[(size_t)k * 256 + j];
#pragma unroll
    for (int m = 0; m < 16; ++m) acc[m] += in_l[m][k] * w;
  }
#pragma unroll
  for (int m = 0; m < 16; ++m)
    out[(size_t)(m0 + m) * 256 + j] = fmaxf(acc[m], 0.f);
}

__global__ void mlp_out_k(const float* __restrict__ in, const float* __restrict__ W,
                          const float* __restrict__ bias, float* __restrict__ out) {
  int wave = threadIdx.x >> 6, lane = threadIdx.x & 63;
  int m = blockIdx.x * 4 + wave;
  if (m >= K_N_MOLS) return;
  float4 v = *(const float4*)(in + (size_t)m * 256 + lane * 4);
  float4 w = *(const float4*)(W + lane * 4);
  float s = v.x * w.x + v.y * w.y + v.z * w.z + v.w * w.w;
  for (int off = 32; off; off >>= 1) s += __shfl_down(s, off);
  if (lane == 0) out[m] = s + bias[0];
}

extern "C" void kernel_launch(void* const* d_in, const int* in_sizes, int n_in,
                              void* d_out, int out_size, void* d_ws, size_t ws_size,
                              hipStream_t stream) {
  const float* atom_states = (const float*)d_in[0];
  const int* esrc = (const int*)d_in[1];
  const int* edst = (const int*)d_in[2];
  const int* mol_ids = (const int*)d_in[3];
  const float* msWin = (const float*)d_in[4];
  const float* msbin = (const float*)d_in[5];
  const float* msWh = (const float*)d_in[6];
  const float* msbh = (const float*)d_in[7];
  const float* msWout = (const float*)d_in[8];
  const float* msbout = (const float*)d_in[9];
  const float* roWin = (const float*)d_in[10];
  const float* robin = (const float*)d_in[11];
  const float* roWh = (const float*)d_in[12];
  const float* robh = (const float*)d_in[13];
  const float* roWout = (const float*)d_in[14];
  const float* robout = (const float*)d_in[15];
  float* out = (float*)d_out;

  // workspace carve-out (~94 MB)
  unsigned short* m_buf = (unsigned short*)d_ws;            // 400000*64 bf16 = 51.2MB
  float* sA = (float*)(m_buf + (size_t)K_N_EDGES * 64);     // 100000*64 f32 = 25.6MB
  unsigned short* stb = (unsigned short*)(sA + (size_t)K_N_ATOMS * 64);  // 12.8MB
  int* es = (int*)(stb + (size_t)K_N_ATOMS * 64);           // 400000
  int* ed = es + K_N_EDGES;                                 // 400000
  int* cnt = ed + K_N_EDGES;                                // 100000
  int* start = cnt + K_N_ATOMS;                             // 100001
  int* cur = start + K_N_ATOMS + 1;                         // 100000
  int* partial = cur + K_N_ATOMS;                           // 512
  unsigned short* wfb = (unsigned short*)(partial + 512);   // 3*40960 bf16
  // readout aliases into m_buf (free after last seg_agg)
  float* mol = (float*)m_buf;                               // 4000*64
  float* r1 = mol + (size_t)K_N_MOLS * 64;                  // 4000*256
  float* r2 = r1 + (size_t)K_N_MOLS * 256;                  // 4000*256
  int* mstart = (int*)(r2 + (size_t)K_N_MOLS * 256);        // 4001

  const int EG = (K_N_EDGES + 255) / 256;   // 1563
  const int AG = (K_N_ATOMS + 255) / 256;   // 391
  const int N8 = K_N_ATOMS * 64 / 8;        // 800000

  prep_w<<<dim3(40, 3), 256, 0, stream>>>(msWin, msWh, msWout, wfb);
  st2bf<<<(N8 + 255) / 256, 256, 0, stream>>>(atom_states, stb, N8);

  // counting sort of edges by src -> CSR
  hipMemsetAsync(cnt, 0, K_N_ATOMS * sizeof(int), stream);
  k_hist<<<EG, 256, 0, stream>>>(esrc, cnt);
  k_blocksum<<<AG, 256, 0, stream>>>(cnt, partial);
  k_scanpart<<<1, 64, 0, stream>>>(partial, AG);
  k_scanfinal<<<AG, 256, 0, stream>>>(cnt, partial, start, cur);
  k_scatter<<<EG, 256, 0, stream>>>(esrc, edst, cur, es, ed);

  for (int s = 0; s < 3; ++s) {
    edge_msg<<<EG, 256, 0, stream>>>(stb, m_buf, es, ed, wfb + s * 40960,
                                     msbin + s * 128, msbh + s * 128, msbout + s * 64);
    seg_agg<<<(K_N_ATOMS * 64 + 255) / 256, 256, 0, stream>>>(m_buf, start, sA, stb);
  }

  // readout
  mol_bounds<<<AG, 256, 0, stream>>>(mol_ids, mstart);
  mol_sum<<<K_N_MOLS / 4, 256, 0, stream>>>(sA, mstart, mol);
  mlp_layer<64><<<K_N_MOLS / 16, 256, 0, stream>>>(mol, roWin, robin, r1);
  mlp_layer<256><<<K_N_MOLS / 16, 256, 0, stream>>>(r1, roWh, robh, r2);
  mlp_layer<256><<<K_N_MOLS / 16, 256, 0, stream>>>(r2, roWh + 256 * 256, robh + 256, r1);
  mlp_out_k<<<K_N_MOLS / 4, 256, 0, stream>>>(r1, roWout, robout, out);
}

// Round 5
// 510.671 us; speedup vs baseline: 2.8093x; 1.0543x over previous
//
#include <hip/hip_runtime.h>
#include <hip/hip_bf16.h>

#define K_N_ATOMS 100000
#define K_N_EDGES 400000
#define K_N_MOLS  4000

typedef __attribute__((ext_vector_type(8))) short bf16x8;
typedef __attribute__((ext_vector_type(4))) float f32x4;

__device__ __forceinline__ unsigned short f2bf(float x) {
  union { __hip_bfloat16 b; unsigned short u; } c;
  c.b = __float2bfloat16(x);
  return c.u;
}

__device__ __forceinline__ unsigned pk2(float a, float b) {
  union { __hip_bfloat162 h; unsigned u; } c;
  c.h = __float22bfloat162_rn(make_float2(a, b));
  return c.u;
}

__device__ __forceinline__ bf16x8 pack8(float4 x, float4 y) {
  union { bf16x8 v; unsigned u[4]; } r;
  r.u[0] = pk2(x.x, x.y); r.u[1] = pk2(x.z, x.w);
  r.u[2] = pk2(y.x, y.y); r.u[3] = pk2(y.z, y.w);
  return r.v;
}

__device__ __forceinline__ float relu(float x) { return fmaxf(x, 0.f); }

// ---- weight prep: f32 row-major [128][J] -> bf16 A-fragment-linear global ----
__global__ void prep_w(const float* __restrict__ Win, const float* __restrict__ Wh,
                       const float* __restrict__ Wout, unsigned short* __restrict__ wf) {
  int s = blockIdx.y;
  int flat = (blockIdx.x * 256 + threadIdx.x) * 4;  // 40960 elems, grid.x = 40
  const float* W; unsigned short* dst; int jbits, local;
  if (flat < 16384)      { W = Win + s * 16384; dst = wf + s * 40960;         local = flat;         jbits = 7; }
  else if (flat < 32768) { W = Wh  + s * 16384; dst = wf + s * 40960 + 16384; local = flat - 16384; jbits = 7; }
  else                   { W = Wout+ s * 8192;  dst = wf + s * 40960 + 32768; local = flat - 32768; jbits = 6; }
  int k = local >> jbits, j = local & ((1 << jbits) - 1);
  float4 w4 = *(const float4*)(W + local);
  float wv[4] = {w4.x, w4.y, w4.z, w4.w};
  int ks = k >> 5, kr = (k >> 3) & 3, i = k & 7;
#pragma unroll
  for (int c = 0; c < 4; ++c) {
    int jj = j + c;
    int jt = jj >> 4, ln = (jj & 15) + 16 * kr;
    dst[((jt * 4 + ks) * 64 + ln) * 8 + i] = f2bf(wv[c]);
  }
}

// ---- f32 states -> bf16 mirror (input only) ----
__global__ void st2bf(const float* __restrict__ in, unsigned short* __restrict__ out, int n8) {
  int t = blockIdx.x * 256 + threadIdx.x;
  if (t >= n8) return;
  float4 x = ((const float4*)in)[t * 2];
  float4 y = ((const float4*)in)[t * 2 + 1];
  ((bf16x8*)out)[t] = pack8(x, y);
}

// ---- counting sort of edges by src ----
__global__ void k_hist(const int* __restrict__ esrc, int* __restrict__ cnt) {
  int t = blockIdx.x * 256 + threadIdx.x;
  if (t < K_N_EDGES) atomicAdd(&cnt[esrc[t]], 1);
}

__global__ void k_blocksum(const int* __restrict__ cnt, int* __restrict__ partial) {
  __shared__ int red[256];
  int i = blockIdx.x * 256 + threadIdx.x;
  red[threadIdx.x] = (i < K_N_ATOMS) ? cnt[i] : 0;
  __syncthreads();
  for (int off = 128; off; off >>= 1) {
    if (threadIdx.x < off) red[threadIdx.x] += red[threadIdx.x + off];
    __syncthreads();
  }
  if (!threadIdx.x) partial[blockIdx.x] = red[0];
}

__global__ void k_scanpart(int* __restrict__ partial, int nb) {
  if (threadIdx.x == 0 && blockIdx.x == 0) {
    int acc = 0;
    for (int b = 0; b < nb; ++b) { int t = partial[b]; partial[b] = acc; acc += t; }
  }
}

__global__ void k_scanfinal(const int* __restrict__ cnt, const int* __restrict__ poffs,
                            int* __restrict__ start, int* __restrict__ cur) {
  __shared__ int sh[256];
  int tid = threadIdx.x;
  int i = blockIdx.x * 256 + tid;
  int v = (i < K_N_ATOMS) ? cnt[i] : 0;
  sh[tid] = v;
  __syncthreads();
  for (int off = 1; off < 256; off <<= 1) {
    int t = (tid >= off) ? sh[tid - off] : 0;
    __syncthreads();
    sh[tid] += t;
    __syncthreads();
  }
  int ex = sh[tid] - v + poffs[blockIdx.x];
  if (i < K_N_ATOMS) { start[i] = ex; cur[i] = ex; }
  if (i == K_N_ATOMS - 1) start[K_N_ATOMS] = ex + v;
}

__global__ void k_scatter(const int* __restrict__ esrc, const int* __restrict__ edst,
                          int* __restrict__ cur, int2* __restrict__ ep) {
  int t = blockIdx.x * 256 + threadIdx.x;
  if (t < K_N_EDGES) {
    int s = esrc[t];
    int p = atomicAdd(&cur[s], 1);
    ep[p] = make_int2(s, edst[t]);
  }
}

// ---- edge MLP: 32 edges/wave (2 e-tiles), 3 layers MFMA, bf16 msg stores ----
__device__ __forceinline__ void layer128_2(const unsigned short* __restrict__ wf,
                                           const float* __restrict__ bias,
                                           bf16x8 (&bfr)[2][4], unsigned (&p)[2][8][2],
                                           int lane, int h) {
#pragma unroll
  for (int jt = 0; jt < 8; ++jt) {
    f32x4 bv = *(const f32x4*)(bias + jt * 16 + h * 4);
    f32x4 a0 = bv, a1 = bv;
#pragma unroll
    for (int ks = 0; ks < 4; ++ks) {
      bf16x8 a = *(const bf16x8*)(wf + ((jt * 4 + ks) * 64 + lane) * 8);
      a0 = __builtin_amdgcn_mfma_f32_16x16x32_bf16(a, bfr[0][ks], a0, 0, 0, 0);
      a1 = __builtin_amdgcn_mfma_f32_16x16x32_bf16(a, bfr[1][ks], a1, 0, 0, 0);
    }
    p[0][jt][0] = pk2(relu(a0[0]), relu(a0[1])); p[0][jt][1] = pk2(relu(a0[2]), relu(a0[3]));
    p[1][jt][0] = pk2(relu(a1[0]), relu(a1[1])); p[1][jt][1] = pk2(relu(a1[2]), relu(a1[3]));
  }
}

__device__ __forceinline__ void transpose_p2(const unsigned (&p)[2][8][2], bf16x8 (&bfr)[2][4],
                                             int lo, int h) {
  const int hsel = (h & 1) * 2;
#pragma unroll
  for (int et = 0; et < 2; ++et) {
#pragma unroll
    for (int ks = 0; ks < 4; ++ks) {
      union { unsigned u[4]; bf16x8 v; } cv;
#pragma unroll
      for (int w = 0; w < 4; ++w) {
        int srcLane = lo + 16 * (hsel + (w >> 1));
        unsigned d0 = (unsigned)__shfl((int)p[et][2 * ks][w & 1], srcLane, 64);
        unsigned d1 = (unsigned)__shfl((int)p[et][2 * ks + 1][w & 1], srcLane, 64);
        cv.u[w] = (h < 2) ? d0 : d1;
      }
      bfr[et][ks] = cv.v;
    }
  }
}

__global__ __launch_bounds__(256, 4) void edge_msg(
    const unsigned short* __restrict__ stb, unsigned short* __restrict__ m_buf,
    const int2* __restrict__ ep, const unsigned short* __restrict__ wf,
    const float* __restrict__ b1, const float* __restrict__ b2, const float* __restrict__ b3) {
  const int tid = threadIdx.x;
  const int wave = tid >> 6, lane = tid & 63, lo = lane & 15, h = lane >> 4;
  const int ebase = blockIdx.x * 128 + wave * 32;

  int srcs[2], dsts[2];
  unsigned vmask = 0;
#pragma unroll
  for (int et = 0; et < 2; ++et) {
    int e = ebase + et * 16 + lo;
    if (e < K_N_EDGES) vmask |= 1u << et;
    int ec = (e < K_N_EDGES) ? e : (K_N_EDGES - 1);
    int2 pr = ep[ec];
    srcs[et] = pr.x;
    dsts[et] = pr.y;
  }

  // layer-1 B-frags: lane needs act[e][k = ks*32 + h*8 + i]
  bf16x8 bfr[2][4];
#pragma unroll
  for (int et = 0; et < 2; ++et) {
    const unsigned short* rs = stb + (size_t)srcs[et] * 64 + h * 8;
    const unsigned short* rd = stb + (size_t)dsts[et] * 64 + h * 8;
    bfr[et][0] = *(const bf16x8*)(rs);
    bfr[et][1] = *(const bf16x8*)(rs + 32);
    bfr[et][2] = *(const bf16x8*)(rd);
    bfr[et][3] = *(const bf16x8*)(rd + 32);
  }

  unsigned p[2][8][2];
  layer128_2(wf, b1, bfr, p, lane, h);
  transpose_p2(p, bfr, lo, h);
  layer128_2(wf + 16384, b2, bfr, p, lane, h);
  transpose_p2(p, bfr, lo, h);

  const unsigned short* w3 = wf + 32768;
#pragma unroll
  for (int jt = 0; jt < 4; ++jt) {
    f32x4 bv = *(const f32x4*)(b3 + jt * 16 + h * 4);
    f32x4 a0 = bv, a1 = bv;
#pragma unroll
    for (int ks = 0; ks < 4; ++ks) {
      bf16x8 a = *(const bf16x8*)(w3 + ((jt * 4 + ks) * 64 + lane) * 8);
      a0 = __builtin_amdgcn_mfma_f32_16x16x32_bf16(a, bfr[0][ks], a0, 0, 0, 0);
      a1 = __builtin_amdgcn_mfma_f32_16x16x32_bf16(a, bfr[1][ks], a1, 0, 0, 0);
    }
    f32x4 accs[2] = {a0, a1};
#pragma unroll
    for (int et = 0; et < 2; ++et) {
      if (vmask & (1u << et)) {
        int e = ebase + et * 16 + lo;
        *(uint2*)(m_buf + (size_t)e * 64 + jt * 16 + h * 4) =
            make_uint2(pk2(relu(accs[et][0]), relu(accs[et][1])),
                       pk2(relu(accs[et][2]), relu(accs[et][3])));
      }
    }
  }
}

// ---- segmented aggregation: one wave per atom, bf16 output only ----
__global__ __launch_bounds__(256) void seg_agg(
    const unsigned short* __restrict__ m_buf, const int* __restrict__ start,
    unsigned short* __restrict__ stb_out) {
  int wv = (blockIdx.x * 256 + threadIdx.x) >> 6;
  int lane = threadIdx.x & 63;
  if (wv >= K_N_ATOMS) return;
  int s = start[wv], e = start[wv + 1];
  float acc = 0.f;
  int r = s;
  for (; r + 4 <= e; r += 4) {
    float v0 = __bfloat162float(*(const __hip_bfloat16*)(m_buf + (size_t)(r + 0) * 64 + lane));
    float v1 = __bfloat162float(*(const __hip_bfloat16*)(m_buf + (size_t)(r + 1) * 64 + lane));
    float v2 = __bfloat162float(*(const __hip_bfloat16*)(m_buf + (size_t)(r + 2) * 64 + lane));
    float v3 = __bfloat162float(*(const __hip_bfloat16*)(m_buf + (size_t)(r + 3) * 64 + lane));
    acc += (v0 + v1) + (v2 + v3);
  }
  for (; r < e; ++r)
    acc += __bfloat162float(*(const __hip_bfloat16*)(m_buf + (size_t)r * 64 + lane));
  stb_out[(size_t)wv * 64 + lane] = f2bf(acc);
}

// ---- readout ----
__global__ void mol_bounds(const int* __restrict__ mol_ids, int* __restrict__ start) {
  int a = blockIdx.x * 256 + threadIdx.x;
  if (a >= K_N_ATOMS) return;
  int id = mol_ids[a];
  int prev = (a == 0) ? -1 : mol_ids[a - 1];
  for (int m = prev + 1; m <= id; ++m) start[m] = a;
  if (a == K_N_ATOMS - 1)
    for (int m = id + 1; m <= K_N_MOLS; ++m) start[m] = K_N_ATOMS;
}

__global__ void mol_sum(const unsigned short* __restrict__ stb, const int* __restrict__ start,
                        float* __restrict__ mol) {
  int wv = (blockIdx.x * 256 + threadIdx.x) >> 6;
  int lane = threadIdx.x & 63;
  if (wv >= K_N_MOLS) return;
  int s = start[wv], e = start[wv + 1];
  float acc = 0.f;
  for (int a = s; a < e; ++a)
    acc += __bfloat162float(*(const __hip_bfloat16*)(stb + (size_t)a * 64 + lane));
  mol[(size_t)wv * 64 + lane] = acc;
}

template<int KDIM>
__global__ void mlp_layer(const float* __restrict__ in, const float* __restrict__ W,
                          const float* __restrict__ bias, float* __restrict__ out) {
  __shared__ float in_l[16][KDIM + 4];
  int m0 = blockIdx.x * 16;
  int t = threadIdx.x;
  for (int flat = t; flat < 16 * KDIM; flat += 256) {
    int m = flat / KDIM, k = flat - m * KDIM;
    in_l[m][k] = in[(size_t)(m0 + m) * KDIM + k];
  }
  __syncthreads();
  int j = t;
  float b = bias[j];
  float acc[16];
#pragma unroll
  for (int m = 0; m < 16; ++m) acc[m] = b;
  for (int k = 0; k < KDIM; ++k) {
    float w = W[(size_t)k * 256 + j];
#pragma unroll
    for (int m = 0; m < 16; ++m) acc[m] += in_l[m][k] * w;
  }
#pragma unroll
  for (int m = 0; m < 16; ++m)
    out[(size_t)(m0 + m) * 256 + j] = fmaxf(acc[m], 0.f);
}

__global__ void mlp_out_k(const float* __restrict__ in, const float* __restrict__ W,
                          const float* __restrict__ bias, float* __restrict__ out) {
  int wave = threadIdx.x >> 6, lane = threadIdx.x & 63;
  int m = blockIdx.x * 4 + wave;
  if (m >= K_N_MOLS) return;
  float4 v = *(const float4*)(in + (size_t)m * 256 + lane * 4);
  float4 w = *(const float4*)(W + lane * 4);
  float s = v.x * w.x + v.y * w.y + v.z * w.z + v.w * w.w;
  for (int off = 32; off; off >>= 1) s += __shfl_down(s, off);
  if (lane == 0) out[m] = s + bias[0];
}

extern "C" void kernel_launch(void* const* d_in, const int* in_sizes, int n_in,
                              void* d_out, int out_size, void* d_ws, size_t ws_size,
                              hipStream_t stream) {
  const float* atom_states = (const float*)d_in[0];
  const int* esrc = (const int*)d_in[1];
  const int* edst = (const int*)d_in[2];
  const int* mol_ids = (const int*)d_in[3];
  const float* msWin = (const float*)d_in[4];
  const float* msbin = (const float*)d_in[5];
  const float* msWh = (const float*)d_in[6];
  const float* msbh = (const float*)d_in[7];
  const float* msWout = (const float*)d_in[8];
  const float* msbout = (const float*)d_in[9];
  const float* roWin = (const float*)d_in[10];
  const float* robin = (const float*)d_in[11];
  const float* roWh = (const float*)d_in[12];
  const float* robh = (const float*)d_in[13];
  const float* roWout = (const float*)d_in[14];
  const float* robout = (const float*)d_in[15];
  float* out = (float*)d_out;

  // workspace carve-out
  unsigned short* m_buf = (unsigned short*)d_ws;            // 400000*64 bf16 = 51.2MB
  unsigned short* stb = m_buf + (size_t)K_N_EDGES * 64;     // 100000*64 bf16 = 12.8MB
  int2* ep = (int2*)(stb + (size_t)K_N_ATOMS * 64);         // 400000 int2
  int* cnt = (int*)(ep + K_N_EDGES);                        // 100000
  int* start = cnt + K_N_ATOMS;                             // 100001
  int* cur = start + K_N_ATOMS + 1;                         // 100000
  int* partial = cur + K_N_ATOMS;                           // 512
  unsigned short* wfb = (unsigned short*)(partial + 512);   // 3*40960 bf16
  // readout aliases into m_buf (free after last seg_agg)
  float* mol = (float*)m_buf;                               // 4000*64
  float* r1 = mol + (size_t)K_N_MOLS * 64;                  // 4000*256
  float* r2 = r1 + (size_t)K_N_MOLS * 256;                  // 4000*256
  int* mstart = (int*)(r2 + (size_t)K_N_MOLS * 256);        // 4001

  const int EG = (K_N_EDGES + 255) / 256;    // 1563
  const int EG2 = (K_N_EDGES + 127) / 128;   // 3125
  const int AG = (K_N_ATOMS + 255) / 256;    // 391
  const int N8 = K_N_ATOMS * 64 / 8;         // 800000

  prep_w<<<dim3(40, 3), 256, 0, stream>>>(msWin, msWh, msWout, wfb);
  st2bf<<<(N8 + 255) / 256, 256, 0, stream>>>(atom_states, stb, N8);

  // counting sort of edges by src -> CSR
  hipMemsetAsync(cnt, 0, K_N_ATOMS * sizeof(int), stream);
  k_hist<<<EG, 256, 0, stream>>>(esrc, cnt);
  k_blocksum<<<AG, 256, 0, stream>>>(cnt, partial);
  k_scanpart<<<1, 64, 0, stream>>>(partial, AG);
  k_scanfinal<<<AG, 256, 0, stream>>>(cnt, partial, start, cur);
  k_scatter<<<EG, 256, 0, stream>>>(esrc, edst, cur, ep);

  for (int s = 0; s < 3; ++s) {
    edge_msg<<<EG2, 256, 0, stream>>>(stb, m_buf, ep, wfb + s * 40960,
                                      msbin + s * 128, msbh + s * 128, msbout + s * 64);
    seg_agg<<<(K_N_ATOMS * 64 + 255) / 256, 256, 0, stream>>>(m_buf, start, stb);
  }

  // readout
  mol_bounds<<<AG, 256, 0, stream>>>(mol_ids, mstart);
  mol_sum<<<K_N_MOLS / 4, 256, 0, stream>>>(stb, mstart, mol);
  mlp_layer<64><<<K_N_MOLS / 16, 256, 0, stream>>>(mol, roWin, robin, r1);
  mlp_layer<256><<<K_N_MOLS / 16, 256, 0, stream>>>(r1, roWh, robh, r2);
  mlp_layer<256><<<K_N_MOLS / 16, 256, 0, stream>>>(r2, roWh + 256 * 256, robh + 256, r1);
  mlp_out_k<<<K_N_MOLS / 4, 256, 0, stream>>>(r1, roWout, robout, out);
}

// Round 6
// 472.766 us; speedup vs baseline: 3.0345x; 1.0802x over previous
//
#include <hip/hip_runtime.h>
#include <hip/hip_bf16.h>

#define K_N_ATOMS 100000
#define K_N_EDGES 400000
#define K_N_MOLS  4000

typedef __attribute__((ext_vector_type(8))) short bf16x8;
typedef __attribute__((ext_vector_type(4))) float f32x4;

__device__ __forceinline__ unsigned short f2bf(float x) {
  union { __hip_bfloat16 b; unsigned short u; } c;
  c.b = __float2bfloat16(x);
  return c.u;
}

__device__ __forceinline__ float bf2f(unsigned short u) {
  union { float f; unsigned u; } c;
  c.u = ((unsigned)u) << 16;
  return c.f;
}

__device__ __forceinline__ unsigned pk2(float a, float b) {
  union { __hip_bfloat162 h; unsigned u; } c;
  c.h = __float22bfloat162_rn(make_float2(a, b));
  return c.u;
}

__device__ __forceinline__ bf16x8 pack8(float4 x, float4 y) {
  union { bf16x8 v; unsigned u[4]; } r;
  r.u[0] = pk2(x.x, x.y); r.u[1] = pk2(x.z, x.w);
  r.u[2] = pk2(y.x, y.y); r.u[3] = pk2(y.z, y.w);
  return r.v;
}

__device__ __forceinline__ float relu(float x) { return fmaxf(x, 0.f); }

// h1 fragment: relu(F + G) elementwise on bf16x8
__device__ __forceinline__ bf16x8 addrelu8(bf16x8 a, bf16x8 b) {
  union { bf16x8 v; unsigned short s[8]; } ua, ub;
  ua.v = a; ub.v = b;
  union { bf16x8 v; unsigned u[4]; } r;
#pragma unroll
  for (int q = 0; q < 4; ++q) {
    float x0 = relu(bf2f(ua.s[2 * q]) + bf2f(ub.s[2 * q]));
    float x1 = relu(bf2f(ua.s[2 * q + 1]) + bf2f(ub.s[2 * q + 1]));
    r.u[q] = pk2(x0, x1);
  }
  return r.v;
}

// ---- weight prep ----
// per step s, layout in wf + s*40960 (shorts):
//   [0,16384)      wfg: A-frags of W' [64 x 256], W'[k][j]= j<128? Win[k][j] : Win[64+k][j-128]
//                  idx ((jt*2+ks)*64+ln)*8+i , jt0..15 ks0..1
//   [16384,32768)  w2:  A-frags of Wh [128 x 128], idx ((jt*4+ks)*64+ln)*8+i
//   [32768,40960)  w3:  A-frags of Wout [128 x 64]
__global__ void prep_w(const float* __restrict__ Win, const float* __restrict__ Wh,
                       const float* __restrict__ Wout, unsigned short* __restrict__ wf) {
  int s = blockIdx.y;
  int flat = (blockIdx.x * 256 + threadIdx.x) * 4;  // 40960 elems, grid.x = 40
  if (flat < 16384) {
    const float* W = Win + s * 16384;
    unsigned short* dst = wf + s * 40960;
    int k = flat >> 7, j = flat & 127;
    float4 w4 = *(const float4*)(W + flat);
    float wv[4] = {w4.x, w4.y, w4.z, w4.w};
#pragma unroll
    for (int c = 0; c < 4; ++c) {
      int jj = j + c, kk = k;
      if (k >= 64) { kk = k - 64; jj += 128; }
      int jt = jj >> 4, ks = kk >> 5, ln = (jj & 15) + 16 * ((kk >> 3) & 3), i = kk & 7;
      dst[((jt * 2 + ks) * 64 + ln) * 8 + i] = f2bf(wv[c]);
    }
  } else if (flat < 32768) {
    const float* W = Wh + s * 16384;
    unsigned short* dst = wf + s * 40960 + 16384;
    int local = flat - 16384;
    int k = local >> 7, j = local & 127;
    float4 w4 = *(const float4*)(W + local);
    float wv[4] = {w4.x, w4.y, w4.z, w4.w};
    int ks = k >> 5, kr = (k >> 3) & 3, i = k & 7;
#pragma unroll
    for (int c = 0; c < 4; ++c) {
      int jj = j + c;
      int jt = jj >> 4, ln = (jj & 15) + 16 * kr;
      dst[((jt * 4 + ks) * 64 + ln) * 8 + i] = f2bf(wv[c]);
    }
  } else {
    const float* W = Wout + s * 8192;
    unsigned short* dst = wf + s * 40960 + 32768;
    int local = flat - 32768;
    int k = local >> 6, j = local & 63;
    float4 w4 = *(const float4*)(W + local);
    float wv[4] = {w4.x, w4.y, w4.z, w4.w};
    int ks = k >> 5, kr = (k >> 3) & 3, i = k & 7;
#pragma unroll
    for (int c = 0; c < 4; ++c) {
      int jj = j + c;
      int jt = jj >> 4, ln = (jj & 15) + 16 * kr;
      dst[((jt * 4 + ks) * 64 + ln) * 8 + i] = f2bf(wv[c]);
    }
  }
}

// ---- f32 states -> bf16 mirror (input only) ----
__global__ void st2bf(const float* __restrict__ in, unsigned short* __restrict__ out, int n8) {
  int t = blockIdx.x * 256 + threadIdx.x;
  if (t >= n8) return;
  float4 x = ((const float4*)in)[t * 2];
  float4 y = ((const float4*)in)[t * 2 + 1];
  ((bf16x8*)out)[t] = pack8(x, y);
}

// ---- counting sort of edges by src ----
__global__ void k_hist(const int* __restrict__ esrc, int* __restrict__ cnt) {
  int t = blockIdx.x * 256 + threadIdx.x;
  if (t < K_N_EDGES) atomicAdd(&cnt[esrc[t]], 1);
}

__global__ void k_blocksum(const int* __restrict__ cnt, int* __restrict__ partial) {
  __shared__ int red[256];
  int i = blockIdx.x * 256 + threadIdx.x;
  red[threadIdx.x] = (i < K_N_ATOMS) ? cnt[i] : 0;
  __syncthreads();
  for (int off = 128; off; off >>= 1) {
    if (threadIdx.x < off) red[threadIdx.x] += red[threadIdx.x + off];
    __syncthreads();
  }
  if (!threadIdx.x) partial[blockIdx.x] = red[0];
}

// single-block LDS scan of block partials (exclusive) -- replaces serial 1-thread scan
__global__ void k_scanpart2(int* __restrict__ partial, int nb) {
  __shared__ int sh[512];
  int tid = threadIdx.x;
  int v = (tid < nb) ? partial[tid] : 0;
  sh[tid] = v;
  __syncthreads();
  for (int off = 1; off < 512; off <<= 1) {
    int t = (tid >= off) ? sh[tid - off] : 0;
    __syncthreads();
    sh[tid] += t;
    __syncthreads();
  }
  if (tid < nb) partial[tid] = sh[tid] - v;  // exclusive prefix
}

__global__ void k_scanfinal(const int* __restrict__ cnt, const int* __restrict__ poffs,
                            int* __restrict__ start, int* __restrict__ cur) {
  __shared__ int sh[256];
  int tid = threadIdx.x;
  int i = blockIdx.x * 256 + tid;
  int v = (i < K_N_ATOMS) ? cnt[i] : 0;
  sh[tid] = v;
  __syncthreads();
  for (int off = 1; off < 256; off <<= 1) {
    int t = (tid >= off) ? sh[tid - off] : 0;
    __syncthreads();
    sh[tid] += t;
    __syncthreads();
  }
  int ex = sh[tid] - v + poffs[blockIdx.x];
  if (i < K_N_ATOMS) { start[i] = ex; cur[i] = ex; }
  if (i == K_N_ATOMS - 1) start[K_N_ATOMS] = ex + v;
}

__global__ void k_scatter(const int* __restrict__ esrc, const int* __restrict__ edst,
                          int* __restrict__ cur, int2* __restrict__ ep) {
  int t = blockIdx.x * 256 + threadIdx.x;
  if (t < K_N_EDGES) {
    int s = esrc[t];
    int p = atomicAdd(&cur[s], 1);
    ep[p] = make_int2(s, edst[t]);
  }
}

// ---- per-atom F/G GEMM: FG[atom][0:128]=states@Win_top + b, [128:256]=states@Win_bot ----
__global__ __launch_bounds__(256, 4) void fg_gemm(
    const unsigned short* __restrict__ stb, unsigned short* __restrict__ FG,
    const unsigned short* __restrict__ wfg, const float* __restrict__ bin) {
  const int tid = threadIdx.x;
  const int wave = tid >> 6, lane = tid & 63, lo = lane & 15, h = lane >> 4;
  const int atom0 = (blockIdx.x * 4 + wave) * 16;
  if (atom0 >= K_N_ATOMS) return;

  // B-frags: states[atom0+lo][k = ks*32 + h*8 + i], ks=0..1 (K=64)
  const unsigned short* row = stb + (size_t)(atom0 + lo) * 64 + h * 8;
  bf16x8 b0 = *(const bf16x8*)(row);
  bf16x8 b1 = *(const bf16x8*)(row + 32);

#pragma unroll
  for (int jt = 0; jt < 16; ++jt) {
    f32x4 acc;
    if (jt < 8) acc = *(const f32x4*)(bin + jt * 16 + h * 4);
    else { acc[0] = 0.f; acc[1] = 0.f; acc[2] = 0.f; acc[3] = 0.f; }
    bf16x8 a0 = *(const bf16x8*)(wfg + ((jt * 2 + 0) * 64 + lane) * 8);
    bf16x8 a1 = *(const bf16x8*)(wfg + ((jt * 2 + 1) * 64 + lane) * 8);
    acc = __builtin_amdgcn_mfma_f32_16x16x32_bf16(a0, b0, acc, 0, 0, 0);
    acc = __builtin_amdgcn_mfma_f32_16x16x32_bf16(a1, b1, acc, 0, 0, 0);
    // D: row j = jt*16 + h*4 + r, col atom = atom0+lo  (NO relu here)
    *(uint2*)(FG + (size_t)(atom0 + lo) * 256 + jt * 16 + h * 4) =
        make_uint2(pk2(acc[0], acc[1]), pk2(acc[2], acc[3]));
  }
}

// ---- edge MLP v3: h1 = relu(F[src]+G[dst]) gathered direct; layers 2,3 MFMA ----
__device__ __forceinline__ void layer128_2(const unsigned short* __restrict__ wf,
                                           const float* __restrict__ bias,
                                           bf16x8 (&bfr)[2][4], unsigned (&p)[2][8][2],
                                           int lane, int h) {
#pragma unroll
  for (int jt = 0; jt < 8; ++jt) {
    f32x4 bv = *(const f32x4*)(bias + jt * 16 + h * 4);
    f32x4 a0 = bv, a1 = bv;
#pragma unroll
    for (int ks = 0; ks < 4; ++ks) {
      bf16x8 a = *(const bf16x8*)(wf + ((jt * 4 + ks) * 64 + lane) * 8);
      a0 = __builtin_amdgcn_mfma_f32_16x16x32_bf16(a, bfr[0][ks], a0, 0, 0, 0);
      a1 = __builtin_amdgcn_mfma_f32_16x16x32_bf16(a, bfr[1][ks], a1, 0, 0, 0);
    }
    p[0][jt][0] = pk2(relu(a0[0]), relu(a0[1])); p[0][jt][1] = pk2(relu(a0[2]), relu(a0[3]));
    p[1][jt][0] = pk2(relu(a1[0]), relu(a1[1])); p[1][jt][1] = pk2(relu(a1[2]), relu(a1[3]));
  }
}

__device__ __forceinline__ void transpose_p2(const unsigned (&p)[2][8][2], bf16x8 (&bfr)[2][4],
                                             int lo, int h) {
  const int hsel = (h & 1) * 2;
#pragma unroll
  for (int et = 0; et < 2; ++et) {
#pragma unroll
    for (int ks = 0; ks < 4; ++ks) {
      union { unsigned u[4]; bf16x8 v; } cv;
#pragma unroll
      for (int w = 0; w < 4; ++w) {
        int srcLane = lo + 16 * (hsel + (w >> 1));
        unsigned d0 = (unsigned)__shfl((int)p[et][2 * ks][w & 1], srcLane, 64);
        unsigned d1 = (unsigned)__shfl((int)p[et][2 * ks + 1][w & 1], srcLane, 64);
        cv.u[w] = (h < 2) ? d0 : d1;
      }
      bfr[et][ks] = cv.v;
    }
  }
}

__global__ __launch_bounds__(256, 4) void edge_msg3(
    const unsigned short* __restrict__ FG, unsigned short* __restrict__ m_buf,
    const int2* __restrict__ ep, const unsigned short* __restrict__ wf23,
    const float* __restrict__ b2, const float* __restrict__ b3) {
  const int tid = threadIdx.x;
  const int wave = tid >> 6, lane = tid & 63, lo = lane & 15, h = lane >> 4;
  const int ebase = blockIdx.x * 128 + wave * 32;

  int srcs[2], dsts[2];
  unsigned vmask = 0;
#pragma unroll
  for (int et = 0; et < 2; ++et) {
    int e = ebase + et * 16 + lo;
    if (e < K_N_EDGES) vmask |= 1u << et;
    int ec = (e < K_N_EDGES) ? e : (K_N_EDGES - 1);
    int2 pr = ep[ec];
    srcs[et] = pr.x;
    dsts[et] = pr.y;
  }

  // h1 B-frags: lane needs h1[e][k = ks*32 + h*8 + i] = relu(F[src][k] + G[dst][k])
  bf16x8 bfr[2][4];
#pragma unroll
  for (int et = 0; et < 2; ++et) {
    const unsigned short* pf = FG + (size_t)srcs[et] * 256 + h * 8;
    const unsigned short* pg = FG + (size_t)dsts[et] * 256 + 128 + h * 8;
#pragma unroll
    for (int ks = 0; ks < 4; ++ks) {
      bf16x8 f = *(const bf16x8*)(pf + ks * 32);
      bf16x8 g = *(const bf16x8*)(pg + ks * 32);
      bfr[et][ks] = addrelu8(f, g);
    }
  }

  unsigned p[2][8][2];
  layer128_2(wf23, b2, bfr, p, lane, h);
  transpose_p2(p, bfr, lo, h);

  const unsigned short* w3 = wf23 + 16384;
#pragma unroll
  for (int jt = 0; jt < 4; ++jt) {
    f32x4 bv = *(const f32x4*)(b3 + jt * 16 + h * 4);
    f32x4 a0 = bv, a1 = bv;
#pragma unroll
    for (int ks = 0; ks < 4; ++ks) {
      bf16x8 a = *(const bf16x8*)(w3 + ((jt * 4 + ks) * 64 + lane) * 8);
      a0 = __builtin_amdgcn_mfma_f32_16x16x32_bf16(a, bfr[0][ks], a0, 0, 0, 0);
      a1 = __builtin_amdgcn_mfma_f32_16x16x32_bf16(a, bfr[1][ks], a1, 0, 0, 0);
    }
    f32x4 accs[2] = {a0, a1};
#pragma unroll
    for (int et = 0; et < 2; ++et) {
      if (vmask & (1u << et)) {
        int e = ebase + et * 16 + lo;
        *(uint2*)(m_buf + (size_t)e * 64 + jt * 16 + h * 4) =
            make_uint2(pk2(relu(accs[et][0]), relu(accs[et][1])),
                       pk2(relu(accs[et][2]), relu(accs[et][3])));
      }
    }
  }
}

// ---- segmented aggregation: 8 lanes per atom, bf16x8 vectorized ----
__global__ __launch_bounds__(256) void seg_agg2(
    const unsigned short* __restrict__ m_buf, const int* __restrict__ start,
    unsigned short* __restrict__ stb_out) {
  int t = blockIdx.x * 256 + threadIdx.x;
  int a = t >> 3, sub = t & 7;
  if (a >= K_N_ATOMS) return;
  int s = start[a], e = start[a + 1];
  float acc[8] = {0.f, 0.f, 0.f, 0.f, 0.f, 0.f, 0.f, 0.f};
  for (int r = s; r < e; ++r) {
    union { bf16x8 v; unsigned short w[8]; } u;
    u.v = *(const bf16x8*)(m_buf + (size_t)r * 64 + sub * 8);
#pragma unroll
    for (int q = 0; q < 8; ++q) acc[q] += bf2f(u.w[q]);
  }
  union { bf16x8 v; unsigned u[4]; } r8;
#pragma unroll
  for (int q = 0; q < 4; ++q) r8.u[q] = pk2(acc[2 * q], acc[2 * q + 1]);
  *(bf16x8*)(stb_out + (size_t)a * 64 + sub * 8) = r8.v;
}

// ---- readout ----
__global__ void mol_bounds(const int* __restrict__ mol_ids, int* __restrict__ start) {
  int a = blockIdx.x * 256 + threadIdx.x;
  if (a >= K_N_ATOMS) return;
  int id = mol_ids[a];
  int prev = (a == 0) ? -1 : mol_ids[a - 1];
  for (int m = prev + 1; m <= id; ++m) start[m] = a;
  if (a == K_N_ATOMS - 1)
    for (int m = id + 1; m <= K_N_MOLS; ++m) start[m] = K_N_ATOMS;
}

__global__ void mol_sum2(const unsigned short* __restrict__ stb, const int* __restrict__ start,
                         float* __restrict__ mol) {
  int t = blockIdx.x * 256 + threadIdx.x;
  int m = t >> 3, sub = t & 7;
  if (m >= K_N_MOLS) return;
  int s = start[m], e = start[m + 1];
  float acc[8] = {0.f, 0.f, 0.f, 0.f, 0.f, 0.f, 0.f, 0.f};
  for (int a = s; a < e; ++a) {
    union { bf16x8 v; unsigned short w[8]; } u;
    u.v = *(const bf16x8*)(stb + (size_t)a * 64 + sub * 8);
#pragma unroll
    for (int q = 0; q < 8; ++q) acc[q] += bf2f(u.w[q]);
  }
  float* p = mol + (size_t)m * 64 + sub * 8;
  *(float4*)(p) = make_float4(acc[0], acc[1], acc[2], acc[3]);
  *(float4*)(p + 4) = make_float4(acc[4], acc[5], acc[6], acc[7]);
}

template<int KDIM>
__global__ void mlp_layer(const float* __restrict__ in, const float* __restrict__ W,
                          const float* __restrict__ bias, float* __restrict__ out) {
  __shared__ float in_l[16][KDIM + 4];
  int m0 = blockIdx.x * 16;
  int t = threadIdx.x;
  for (int flat = t; flat < 16 * KDIM; flat += 256) {
    int m = flat / KDIM, k = flat - m * KDIM;
    in_l[m][k] = in[(size_t)(m0 + m) * KDIM + k];
  }
  __syncthreads();
  int j = t;
  float b = bias[j];
  float acc[16];
#pragma unroll
  for (int m = 0; m < 16; ++m) acc[m] = b;
  for (int k = 0; k < KDIM; ++k) {
    float w = W[(size_t)k * 256 + j];
#pragma unroll
    for (int m = 0; m < 16; ++m) acc[m] += in_l[m][k] * w;
  }
#pragma unroll
  for (int m = 0; m < 16; ++m)
    out[(size_t)(m0 + m) * 256 + j] = fmaxf(acc[m], 0.f);
}

__global__ void mlp_out_k(const float* __restrict__ in, const float* __restrict__ W,
                          const float* __restrict__ bias, float* __restrict__ out) {
  int wave = threadIdx.x >> 6, lane = threadIdx.x & 63;
  int m = blockIdx.x * 4 + wave;
  if (m >= K_N_MOLS) return;
  float4 v = *(const float4*)(in + (size_t)m * 256 + lane * 4);
  float4 w = *(const float4*)(W + lane * 4);
  float s = v.x * w.x + v.y * w.y + v.z * w.z + v.w * w.w;
  for (int off = 32; off; off >>= 1) s += __shfl_down(s, off);
  if (lane == 0) out[m] = s + bias[0];
}

extern "C" void kernel_launch(void* const* d_in, const int* in_sizes, int n_in,
                              void* d_out, int out_size, void* d_ws, size_t ws_size,
                              hipStream_t stream) {
  const float* atom_states = (const float*)d_in[0];
  const int* esrc = (const int*)d_in[1];
  const int* edst = (const int*)d_in[2];
  const int* mol_ids = (const int*)d_in[3];
  const float* msWin = (const float*)d_in[4];
  const float* msbin = (const float*)d_in[5];
  const float* msWh = (const float*)d_in[6];
  const float* msbh = (const float*)d_in[7];
  const float* msWout = (const float*)d_in[8];
  const float* msbout = (const float*)d_in[9];
  const float* roWin = (const float*)d_in[10];
  const float* robin = (const float*)d_in[11];
  const float* roWh = (const float*)d_in[12];
  const float* robh = (const float*)d_in[13];
  const float* roWout = (const float*)d_in[14];
  const float* robout = (const float*)d_in[15];
  float* out = (float*)d_out;

  // workspace carve-out (~121 MB)
  unsigned short* m_buf = (unsigned short*)d_ws;            // 400000*64 bf16 = 51.2MB
  unsigned short* FG = m_buf + (size_t)K_N_EDGES * 64;      // 100000*256 bf16 = 51.2MB
  unsigned short* stb = FG + (size_t)K_N_ATOMS * 256;       // 100000*64 bf16 = 12.8MB
  int2* ep = (int2*)(stb + (size_t)K_N_ATOMS * 64);         // 400000 int2
  int* cnt = (int*)(ep + K_N_EDGES);                        // 100000
  int* start = cnt + K_N_ATOMS;                             // 100001
  int* cur = start + K_N_ATOMS + 1;                         // 100000
  int* partial = cur + K_N_ATOMS;                           // 512
  unsigned short* wfb = (unsigned short*)(partial + 512);   // 3*40960 bf16
  // readout aliases into m_buf (free after last seg_agg2)
  float* mol = (float*)m_buf;                               // 4000*64
  float* r1 = mol + (size_t)K_N_MOLS * 64;                  // 4000*256
  float* r2 = r1 + (size_t)K_N_MOLS * 256;                  // 4000*256
  int* mstart = (int*)(r2 + (size_t)K_N_MOLS * 256);        // 4001

  const int EG = (K_N_EDGES + 255) / 256;    // 1563
  const int EG2 = (K_N_EDGES + 127) / 128;   // 3125
  const int AG = (K_N_ATOMS + 255) / 256;    // 391
  const int N8 = K_N_ATOMS * 64 / 8;         // 800000

  prep_w<<<dim3(40, 3), 256, 0, stream>>>(msWin, msWh, msWout, wfb);
  st2bf<<<(N8 + 255) / 256, 256, 0, stream>>>(atom_states, stb, N8);

  // counting sort of edges by src -> CSR
  hipMemsetAsync(cnt, 0, K_N_ATOMS * sizeof(int), stream);
  k_hist<<<EG, 256, 0, stream>>>(esrc, cnt);
  k_blocksum<<<AG, 256, 0, stream>>>(cnt, partial);
  k_scanpart2<<<1, 512, 0, stream>>>(partial, AG);
  k_scanfinal<<<AG, 256, 0, stream>>>(cnt, partial, start, cur);
  k_scatter<<<EG, 256, 0, stream>>>(esrc, edst, cur, ep);

  for (int s = 0; s < 3; ++s) {
    fg_gemm<<<(K_N_ATOMS / 16 + 3) / 4, 256, 0, stream>>>(
        stb, FG, wfb + s * 40960, msbin + s * 128);
    edge_msg3<<<EG2, 256, 0, stream>>>(FG, m_buf, ep, wfb + s * 40960 + 16384,
                                       msbh + s * 128, msbout + s * 64);
    seg_agg2<<<(K_N_ATOMS * 8 + 255) / 256, 256, 0, stream>>>(m_buf, start, stb);
  }

  // readout
  mol_bounds<<<AG, 256, 0, stream>>>(mol_ids, mstart);
  mol_sum2<<<(K_N_MOLS * 8 + 255) / 256, 256, 0, stream>>>(stb, mstart, mol);
  mlp_layer<64><<<K_N_MOLS / 16, 256, 0, stream>>>(mol, roWin, robin, r1);
  mlp_layer<256><<<K_N_MOLS / 16, 256, 0, stream>>>(r1, roWh, robh, r2);
  mlp_layer<256><<<K_N_MOLS / 16, 256, 0, stream>>>(r2, roWh + 256 * 256, robh + 256, r1);
  mlp_out_k<<<K_N_MOLS / 4, 256, 0, stream>>>(r1, roWout, robout, out);
}

// Round 8
// 383.610 us; speedup vs baseline: 3.7398x; 1.2324x over previous
//
#include <hip/hip_runtime.h>
#include <hip/hip_bf16.h>

#define K_N_ATOMS 100000
#define K_N_EDGES 400000
#define K_N_MOLS  4000

typedef __attribute__((ext_vector_type(8))) short bf16x8;
typedef __attribute__((ext_vector_type(4))) float f32x4;

__device__ __forceinline__ unsigned short f2bf(float x) {
  union { __hip_bfloat16 b; unsigned short u; } c;
  c.b = __float2bfloat16(x);
  return c.u;
}

__device__ __forceinline__ float bf2f(unsigned short u) {
  union { float f; unsigned u; } c;
  c.u = ((unsigned)u) << 16;
  return c.f;
}

__device__ __forceinline__ unsigned pk2(float a, float b) {
  union { __hip_bfloat162 h; unsigned u; } c;
  c.h = __float22bfloat162_rn(make_float2(a, b));
  return c.u;
}

__device__ __forceinline__ bf16x8 pack8(float4 x, float4 y) {
  union { bf16x8 v; unsigned u[4]; } r;
  r.u[0] = pk2(x.x, x.y); r.u[1] = pk2(x.z, x.w);
  r.u[2] = pk2(y.x, y.y); r.u[3] = pk2(y.z, y.w);
  return r.v;
}

__device__ __forceinline__ float relu(float x) { return fmaxf(x, 0.f); }

// h1 fragment: relu(F + G) elementwise on bf16x8
__device__ __forceinline__ bf16x8 addrelu8(bf16x8 a, bf16x8 b) {
  union { bf16x8 v; unsigned short s[8]; } ua, ub;
  ua.v = a; ub.v = b;
  union { bf16x8 v; unsigned u[4]; } r;
#pragma unroll
  for (int q = 0; q < 4; ++q) {
    float x0 = relu(bf2f(ua.s[2 * q]) + bf2f(ub.s[2 * q]));
    float x1 = relu(bf2f(ua.s[2 * q + 1]) + bf2f(ub.s[2 * q + 1]));
    r.u[q] = pk2(x0, x1);
  }
  return r.v;
}

// ---- weight prep ----
// per step s, layout in wf + s*40960 (shorts):
//   [0,16384)      wfg: A-frags of W' [64 x 256], W'[k][j]= j<128? Win[k][j] : Win[64+k][j-128]
//                  idx ((jt*2+ks)*64+ln)*8+i , jt0..15 ks0..1
//   [16384,32768)  w2:  A-frags of Wh [128 x 128], idx ((jt*4+ks)*64+ln)*8+i
//   [32768,40960)  w3:  A-frags of Wout [128 x 64]
__global__ void prep_w(const float* __restrict__ Win, const float* __restrict__ Wh,
                       const float* __restrict__ Wout, unsigned short* __restrict__ wf) {
  int s = blockIdx.y;
  int flat = (blockIdx.x * 256 + threadIdx.x) * 4;  // 40960 elems, grid.x = 40
  if (flat < 16384) {
    const float* W = Win + s * 16384;
    unsigned short* dst = wf + s * 40960;
    int k = flat >> 7, j = flat & 127;
    float4 w4 = *(const float4*)(W + flat);
    float wv[4] = {w4.x, w4.y, w4.z, w4.w};
#pragma unroll
    for (int c = 0; c < 4; ++c) {
      int jj = j + c, kk = k;
      if (k >= 64) { kk = k - 64; jj += 128; }
      int jt = jj >> 4, ks = kk >> 5, ln = (jj & 15) + 16 * ((kk >> 3) & 3), i = kk & 7;
      dst[((jt * 2 + ks) * 64 + ln) * 8 + i] = f2bf(wv[c]);
    }
  } else if (flat < 32768) {
    const float* W = Wh + s * 16384;
    unsigned short* dst = wf + s * 40960 + 16384;
    int local = flat - 16384;
    int k = local >> 7, j = local & 127;
    float4 w4 = *(const float4*)(W + local);
    float wv[4] = {w4.x, w4.y, w4.z, w4.w};
    int ks = k >> 5, kr = (k >> 3) & 3, i = k & 7;
#pragma unroll
    for (int c = 0; c < 4; ++c) {
      int jj = j + c;
      int jt = jj >> 4, ln = (jj & 15) + 16 * kr;
      dst[((jt * 4 + ks) * 64 + ln) * 8 + i] = f2bf(wv[c]);
    }
  } else {
    const float* W = Wout + s * 8192;
    unsigned short* dst = wf + s * 40960 + 32768;
    int local = flat - 32768;
    int k = local >> 6, j = local & 63;
    float4 w4 = *(const float4*)(W + local);
    float wv[4] = {w4.x, w4.y, w4.z, w4.w};
    int ks = k >> 5, kr = (k >> 3) & 3, i = k & 7;
#pragma unroll
    for (int c = 0; c < 4; ++c) {
      int jj = j + c;
      int jt = jj >> 4, ln = (jj & 15) + 16 * kr;
      dst[((jt * 4 + ks) * 64 + ln) * 8 + i] = f2bf(wv[c]);
    }
  }
}

// ---- counting sort of edges by src ----
__global__ void k_hist(const int* __restrict__ esrc, int* __restrict__ cnt) {
  int t = blockIdx.x * 256 + threadIdx.x;
  if (t < K_N_EDGES) atomicAdd(&cnt[esrc[t]], 1);
}

__global__ void k_blocksum(const int* __restrict__ cnt, int* __restrict__ partial) {
  __shared__ int red[256];
  int i = blockIdx.x * 256 + threadIdx.x;
  red[threadIdx.x] = (i < K_N_ATOMS) ? cnt[i] : 0;
  __syncthreads();
  for (int off = 128; off; off >>= 1) {
    if (threadIdx.x < off) red[threadIdx.x] += red[threadIdx.x + off];
    __syncthreads();
  }
  if (!threadIdx.x) partial[blockIdx.x] = red[0];
}

__global__ void k_scanpart2(int* __restrict__ partial, int nb) {
  __shared__ int sh[512];
  int tid = threadIdx.x;
  int v = (tid < nb) ? partial[tid] : 0;
  sh[tid] = v;
  __syncthreads();
  for (int off = 1; off < 512; off <<= 1) {
    int t = (tid >= off) ? sh[tid - off] : 0;
    __syncthreads();
    sh[tid] += t;
    __syncthreads();
  }
  if (tid < nb) partial[tid] = sh[tid] - v;  // exclusive prefix
}

__global__ void k_scanfinal(const int* __restrict__ cnt, const int* __restrict__ poffs,
                            int* __restrict__ start, int* __restrict__ cur) {
  __shared__ int sh[256];
  int tid = threadIdx.x;
  int i = blockIdx.x * 256 + tid;
  int v = (i < K_N_ATOMS) ? cnt[i] : 0;
  sh[tid] = v;
  __syncthreads();
  for (int off = 1; off < 256; off <<= 1) {
    int t = (tid >= off) ? sh[tid - off] : 0;
    __syncthreads();
    sh[tid] += t;
    __syncthreads();
  }
  int ex = sh[tid] - v + poffs[blockIdx.x];
  if (i < K_N_ATOMS) { start[i] = ex; cur[i] = ex; }
  if (i == K_N_ATOMS - 1) start[K_N_ATOMS] = ex + v;
}

__global__ void k_scatter(const int* __restrict__ esrc, const int* __restrict__ edst,
                          int* __restrict__ cur, int2* __restrict__ ep) {
  int t = blockIdx.x * 256 + threadIdx.x;
  if (t < K_N_EDGES) {
    int s = esrc[t];
    int p = atomicAdd(&cur[s], 1);
    ep[p] = make_int2(s, edst[t]);
  }
}

// ---- step-0 F/G GEMM reading f32 states directly ----
__global__ __launch_bounds__(256, 4) void fg_gemm0(
    const float* __restrict__ st_in, unsigned short* __restrict__ FG,
    const unsigned short* __restrict__ wfg, const float* __restrict__ bin) {
  const int tid = threadIdx.x;
  const int wave = tid >> 6, lane = tid & 63, lo = lane & 15, h = lane >> 4;
  const int atom0 = (blockIdx.x * 4 + wave) * 16;
  const int a = atom0 + lo;
  const int ac = (a < K_N_ATOMS) ? a : (K_N_ATOMS - 1);

  const float* row = st_in + (size_t)ac * 64 + h * 8;
  bf16x8 b0 = pack8(*(const float4*)row, *(const float4*)(row + 4));
  bf16x8 b1 = pack8(*(const float4*)(row + 32), *(const float4*)(row + 36));

#pragma unroll
  for (int jt = 0; jt < 16; ++jt) {
    f32x4 acc;
    if (jt < 8) acc = *(const f32x4*)(bin + jt * 16 + h * 4);
    else { acc[0] = 0.f; acc[1] = 0.f; acc[2] = 0.f; acc[3] = 0.f; }
    bf16x8 a0 = *(const bf16x8*)(wfg + ((jt * 2 + 0) * 64 + lane) * 8);
    bf16x8 a1 = *(const bf16x8*)(wfg + ((jt * 2 + 1) * 64 + lane) * 8);
    acc = __builtin_amdgcn_mfma_f32_16x16x32_bf16(a0, b0, acc, 0, 0, 0);
    acc = __builtin_amdgcn_mfma_f32_16x16x32_bf16(a1, b1, acc, 0, 0, 0);
    if (a < K_N_ATOMS)
      *(uint2*)(FG + (size_t)a * 256 + jt * 16 + h * 4) =
          make_uint2(pk2(acc[0], acc[1]), pk2(acc[2], acc[3]));
  }
}

// ---- fused message-aggregation + F/G GEMM (steps 1,2) ----
__global__ __launch_bounds__(256, 4) void agg_fg(
    const unsigned short* __restrict__ m_buf, const int* __restrict__ start,
    unsigned short* __restrict__ FG,
    const unsigned short* __restrict__ wfg, const float* __restrict__ bin) {
  const int tid = threadIdx.x;
  const int wave = tid >> 6, lane = tid & 63, lo = lane & 15, h = lane >> 4;
  const int atom0 = (blockIdx.x * 4 + wave) * 16;
  const int a = atom0 + lo;

  int s = 0, e = 0;
  if (a < K_N_ATOMS) { s = start[a]; e = start[a + 1]; }

  float acc[16];
#pragma unroll
  for (int q = 0; q < 16; ++q) acc[q] = 0.f;
  for (int r = s; r < e; ++r) {
    const unsigned short* p = m_buf + (size_t)r * 64 + h * 8;
    union { bf16x8 v; unsigned short w[8]; } u0, u1;
    u0.v = *(const bf16x8*)(p);
    u1.v = *(const bf16x8*)(p + 32);
#pragma unroll
    for (int q = 0; q < 8; ++q) { acc[q] += bf2f(u0.w[q]); acc[8 + q] += bf2f(u1.w[q]); }
  }
  union { bf16x8 v; unsigned u[4]; } c0, c1;
#pragma unroll
  for (int q = 0; q < 4; ++q) {
    c0.u[q] = pk2(acc[2 * q], acc[2 * q + 1]);
    c1.u[q] = pk2(acc[8 + 2 * q], acc[8 + 2 * q + 1]);
  }
  bf16x8 b0 = c0.v, b1 = c1.v;

#pragma unroll
  for (int jt = 0; jt < 16; ++jt) {
    f32x4 d;
    if (jt < 8) d = *(const f32x4*)(bin + jt * 16 + h * 4);
    else { d[0] = 0.f; d[1] = 0.f; d[2] = 0.f; d[3] = 0.f; }
    bf16x8 a0 = *(const bf16x8*)(wfg + ((jt * 2 + 0) * 64 + lane) * 8);
    bf16x8 a1 = *(const bf16x8*)(wfg + ((jt * 2 + 1) * 64 + lane) * 8);
    d = __builtin_amdgcn_mfma_f32_16x16x32_bf16(a0, b0, d, 0, 0, 0);
    d = __builtin_amdgcn_mfma_f32_16x16x32_bf16(a1, b1, d, 0, 0, 0);
    if (a < K_N_ATOMS)
      *(uint2*)(FG + (size_t)a * 256 + jt * 16 + h * 4) =
          make_uint2(pk2(d[0], d[1]), pk2(d[2], d[3]));
  }
}

// ---- edge MLP: LDS-resident weights, 512 threads, et=2 ----
__device__ __forceinline__ void layer128_2(const unsigned short* wf,
                                           const float* __restrict__ bias,
                                           bf16x8 (&bfr)[2][4], unsigned (&p)[2][8][2],
                                           int lane, int h) {
#pragma unroll
  for (int jt = 0; jt < 8; ++jt) {
    f32x4 bv = *(const f32x4*)(bias + jt * 16 + h * 4);
    f32x4 a0 = bv, a1 = bv;
#pragma unroll
    for (int ks = 0; ks < 4; ++ks) {
      bf16x8 a = *(const bf16x8*)(wf + ((jt * 4 + ks) * 64 + lane) * 8);
      a0 = __builtin_amdgcn_mfma_f32_16x16x32_bf16(a, bfr[0][ks], a0, 0, 0, 0);
      a1 = __builtin_amdgcn_mfma_f32_16x16x32_bf16(a, bfr[1][ks], a1, 0, 0, 0);
    }
    p[0][jt][0] = pk2(relu(a0[0]), relu(a0[1])); p[0][jt][1] = pk2(relu(a0[2]), relu(a0[3]));
    p[1][jt][0] = pk2(relu(a1[0]), relu(a1[1])); p[1][jt][1] = pk2(relu(a1[2]), relu(a1[3]));
  }
}

__device__ __forceinline__ void transpose_p2(const unsigned (&p)[2][8][2], bf16x8 (&bfr)[2][4],
                                             int lo, int h) {
  const int hsel = (h & 1) * 2;
#pragma unroll
  for (int et = 0; et < 2; ++et) {
#pragma unroll
    for (int ks = 0; ks < 4; ++ks) {
      union { unsigned u[4]; bf16x8 v; } cv;
#pragma unroll
      for (int w = 0; w < 4; ++w) {
        int srcLane = lo + 16 * (hsel + (w >> 1));
        unsigned d0 = (unsigned)__shfl((int)p[et][2 * ks][w & 1], srcLane, 64);
        unsigned d1 = (unsigned)__shfl((int)p[et][2 * ks + 1][w & 1], srcLane, 64);
        cv.u[w] = (h < 2) ? d0 : d1;
      }
      bfr[et][ks] = cv.v;
    }
  }
}

__global__ __launch_bounds__(512, 4) void edge_msg4(
    const unsigned short* __restrict__ FG, unsigned short* __restrict__ m_buf,
    const int2* __restrict__ ep, const unsigned short* __restrict__ wf23,
    const float* __restrict__ b2, const float* __restrict__ b3) {
  __shared__ unsigned short wl[24576];  // w2 (16384) + w3 (8192) shorts, 48 KB
  const int tid = threadIdx.x;
  const int wave = tid >> 6, lane = tid & 63, lo = lane & 15, h = lane >> 4;
  const int ebase = blockIdx.x * 256 + wave * 32;

  // issue edge-pair loads first (hide under staging + barrier)
  int srcs[2], dsts[2];
  unsigned vmask = 0;
#pragma unroll
  for (int et = 0; et < 2; ++et) {
    int e = ebase + et * 16 + lo;
    if (e < K_N_EDGES) vmask |= 1u << et;
    int ec = (e < K_N_EDGES) ? e : (K_N_EDGES - 1);
    int2 pr = ep[ec];
    srcs[et] = pr.x;
    dsts[et] = pr.y;
  }

  // stage weights to LDS: 24576 shorts = 3072 bf16x8; 512 thr x 6 iters, coalesced
#pragma unroll
  for (int i = 0; i < 6; ++i)
    ((bf16x8*)wl)[i * 512 + tid] = ((const bf16x8*)wf23)[i * 512 + tid];
  __syncthreads();

  // h1 B-frags: lane needs h1[e][k = ks*32 + h*8 + i] = relu(F[src][k] + G[dst][k])
  bf16x8 bfr[2][4];
#pragma unroll
  for (int et = 0; et < 2; ++et) {
    const unsigned short* pf = FG + (size_t)srcs[et] * 256 + h * 8;
    const unsigned short* pg = FG + (size_t)dsts[et] * 256 + 128 + h * 8;
#pragma unroll
    for (int ks = 0; ks < 4; ++ks) {
      bf16x8 f = *(const bf16x8*)(pf + ks * 32);
      bf16x8 g = *(const bf16x8*)(pg + ks * 32);
      bfr[et][ks] = addrelu8(f, g);
    }
  }

  unsigned p[2][8][2];
  layer128_2(wl, b2, bfr, p, lane, h);
  transpose_p2(p, bfr, lo, h);

  const unsigned short* w3 = wl + 16384;
#pragma unroll
  for (int jt = 0; jt < 4; ++jt) {
    f32x4 bv = *(const f32x4*)(b3 + jt * 16 + h * 4);
    f32x4 a0 = bv, a1 = bv;
#pragma unroll
    for (int ks = 0; ks < 4; ++ks) {
      bf16x8 a = *(const bf16x8*)(w3 + ((jt * 4 + ks) * 64 + lane) * 8);
      a0 = __builtin_amdgcn_mfma_f32_16x16x32_bf16(a, bfr[0][ks], a0, 0, 0, 0);
      a1 = __builtin_amdgcn_mfma_f32_16x16x32_bf16(a, bfr[1][ks], a1, 0, 0, 0);
    }
    f32x4 accs[2] = {a0, a1};
#pragma unroll
    for (int et = 0; et < 2; ++et) {
      if (vmask & (1u << et)) {
        int e = ebase + et * 16 + lo;
        *(uint2*)(m_buf + (size_t)e * 64 + jt * 16 + h * 4) =
            make_uint2(pk2(relu(accs[et][0]), relu(accs[et][1])),
                       pk2(relu(accs[et][2]), relu(accs[et][3])));
      }
    }
  }
}

// ---- final segmented aggregation: 8 lanes per atom, bf16 states out ----
__global__ __launch_bounds__(256) void seg_agg2(
    const unsigned short* __restrict__ m_buf, const int* __restrict__ start,
    unsigned short* __restrict__ stb_out) {
  int t = blockIdx.x * 256 + threadIdx.x;
  int a = t >> 3, sub = t & 7;
  if (a >= K_N_ATOMS) return;
  int s = start[a], e = start[a + 1];
  float acc[8] = {0.f, 0.f, 0.f, 0.f, 0.f, 0.f, 0.f, 0.f};
  for (int r = s; r < e; ++r) {
    union { bf16x8 v; unsigned short w[8]; } u;
    u.v = *(const bf16x8*)(m_buf + (size_t)r * 64 + sub * 8);
#pragma unroll
    for (int q = 0; q < 8; ++q) acc[q] += bf2f(u.w[q]);
  }
  union { bf16x8 v; unsigned u[4]; } r8;
#pragma unroll
  for (int q = 0; q < 4; ++q) r8.u[q] = pk2(acc[2 * q], acc[2 * q + 1]);
  *(bf16x8*)(stb_out + (size_t)a * 64 + sub * 8) = r8.v;
}

// ---- readout ----
__global__ void mol_bounds(const int* __restrict__ mol_ids, int* __restrict__ start) {
  int a = blockIdx.x * 256 + threadIdx.x;
  if (a >= K_N_ATOMS) return;
  int id = mol_ids[a];
  int prev = (a == 0) ? -1 : mol_ids[a - 1];
  for (int m = prev + 1; m <= id; ++m) start[m] = a;
  if (a == K_N_ATOMS - 1)
    for (int m = id + 1; m <= K_N_MOLS; ++m) start[m] = K_N_ATOMS;
}

__global__ void mol_sum2(const unsigned short* __restrict__ stb, const int* __restrict__ start,
                         float* __restrict__ mol) {
  int t = blockIdx.x * 256 + threadIdx.x;
  int m = t >> 3, sub = t & 7;
  if (m >= K_N_MOLS) return;
  int s = start[m], e = start[m + 1];
  float acc[8] = {0.f, 0.f, 0.f, 0.f, 0.f, 0.f, 0.f, 0.f};
  for (int a = s; a < e; ++a) {
    union { bf16x8 v; unsigned short w[8]; } u;
    u.v = *(const bf16x8*)(stb + (size_t)a * 64 + sub * 8);
#pragma unroll
    for (int q = 0; q < 8; ++q) acc[q] += bf2f(u.w[q]);
  }
  float* p = mol + (size_t)m * 64 + sub * 8;
  *(float4*)(p) = make_float4(acc[0], acc[1], acc[2], acc[3]);
  *(float4*)(p + 4) = make_float4(acc[4], acc[5], acc[6], acc[7]);
}

// 8 mols per block, j = thread
template<int KDIM>
__global__ void mlp_layer8(const float* __restrict__ in, const float* __restrict__ W,
                           const float* __restrict__ bias, float* __restrict__ out) {
  __shared__ float in_l[8][KDIM + 4];
  int m0 = blockIdx.x * 8;
  int t = threadIdx.x;
  for (int flat = t; flat < 8 * KDIM; flat += 256) {
    int m = flat / KDIM, k = flat - m * KDIM;
    in_l[m][k] = in[(size_t)(m0 + m) * KDIM + k];
  }
  __syncthreads();
  int j = t;
  float b = bias[j];
  float acc[8];
#pragma unroll
  for (int m = 0; m < 8; ++m) acc[m] = b;
  for (int k = 0; k < KDIM; ++k) {
    float w = W[(size_t)k * 256 + j];
#pragma unroll
    for (int m = 0; m < 8; ++m) acc[m] += in_l[m][k] * w;
  }
#pragma unroll
  for (int m = 0; m < 8; ++m)
    out[(size_t)(m0 + m) * 256 + j] = fmaxf(acc[m], 0.f);
}

__global__ void mlp_out_k(const float* __restrict__ in, const float* __restrict__ W,
                          const float* __restrict__ bias, float* __restrict__ out) {
  int wave = threadIdx.x >> 6, lane = threadIdx.x & 63;
  int m = blockIdx.x * 4 + wave;
  if (m >= K_N_MOLS) return;
  float4 v = *(const float4*)(in + (size_t)m * 256 + lane * 4);
  float4 w = *(const float4*)(W + lane * 4);
  float s = v.x * w.x + v.y * w.y + v.z * w.z + v.w * w.w;
  for (int off = 32; off; off >>= 1) s += __shfl_down(s, off);
  if (lane == 0) out[m] = s + bias[0];
}

extern "C" void kernel_launch(void* const* d_in, const int* in_sizes, int n_in,
                              void* d_out, int out_size, void* d_ws, size_t ws_size,
                              hipStream_t stream) {
  const float* atom_states = (const float*)d_in[0];
  const int* esrc = (const int*)d_in[1];
  const int* edst = (const int*)d_in[2];
  const int* mol_ids = (const int*)d_in[3];
  const float* msWin = (const float*)d_in[4];
  const float* msbin = (const float*)d_in[5];
  const float* msWh = (const float*)d_in[6];
  const float* msbh = (const float*)d_in[7];
  const float* msWout = (const float*)d_in[8];
  const float* msbout = (const float*)d_in[9];
  const float* roWin = (const float*)d_in[10];
  const float* robin = (const float*)d_in[11];
  const float* roWh = (const float*)d_in[12];
  const float* robh = (const float*)d_in[13];
  const float* roWout = (const float*)d_in[14];
  const float* robout = (const float*)d_in[15];
  float* out = (float*)d_out;

  // workspace carve-out
  unsigned short* m_buf = (unsigned short*)d_ws;            // 400000*64 bf16 = 51.2MB
  unsigned short* FG = m_buf + (size_t)K_N_EDGES * 64;      // 100000*256 bf16 = 51.2MB
  unsigned short* stb = FG + (size_t)K_N_ATOMS * 256;       // 100000*64 bf16 = 12.8MB
  int2* ep = (int2*)(stb + (size_t)K_N_ATOMS * 64);         // 400000 int2
  int* cnt = (int*)(ep + K_N_EDGES);                        // 100000
  int* start = cnt + K_N_ATOMS;                             // 100001
  int* cur = start + K_N_ATOMS + 1;                         // 100000
  int* partial = cur + K_N_ATOMS;                           // 512
  unsigned short* wfb = (unsigned short*)(partial + 512);   // 3*40960 bf16
  int* mstart = (int*)(wfb + 3 * 40960);                    // 4001
  // readout aliases into m_buf (free after seg_agg2)
  float* mol = (float*)m_buf;                               // 4000*64
  float* r1 = mol + (size_t)K_N_MOLS * 64;                  // 4000*256
  float* r2 = r1 + (size_t)K_N_MOLS * 256;                  // 4000*256

  const int EG = (K_N_EDGES + 255) / 256;    // 1563 (256 thr)
  const int EG4 = (K_N_EDGES + 255) / 256;   // 1563 (512 thr, 256 edges/block)
  const int AG = (K_N_ATOMS + 255) / 256;    // 391
  const int AG16 = (K_N_ATOMS + 63) / 64;    // 1563 (16 atoms/wave, 4 waves)

  prep_w<<<dim3(40, 3), 256, 0, stream>>>(msWin, msWh, msWout, wfb);

  // counting sort of edges by src -> CSR
  hipMemsetAsync(cnt, 0, K_N_ATOMS * sizeof(int), stream);
  k_hist<<<EG, 256, 0, stream>>>(esrc, cnt);
  k_blocksum<<<AG, 256, 0, stream>>>(cnt, partial);
  k_scanpart2<<<1, 512, 0, stream>>>(partial, AG);
  k_scanfinal<<<AG, 256, 0, stream>>>(cnt, partial, start, cur);
  k_scatter<<<EG, 256, 0, stream>>>(esrc, edst, cur, ep);
  mol_bounds<<<AG, 256, 0, stream>>>(mol_ids, mstart);

  // step 0
  fg_gemm0<<<AG16, 256, 0, stream>>>(atom_states, FG, wfb, msbin);
  edge_msg4<<<EG4, 512, 0, stream>>>(FG, m_buf, ep, wfb + 16384, msbh, msbout);
  // step 1
  agg_fg<<<AG16, 256, 0, stream>>>(m_buf, start, FG, wfb + 40960, msbin + 128);
  edge_msg4<<<EG4, 512, 0, stream>>>(FG, m_buf, ep, wfb + 40960 + 16384,
                                     msbh + 128, msbout + 64);
  // step 2
  agg_fg<<<AG16, 256, 0, stream>>>(m_buf, start, FG, wfb + 81920, msbin + 256);
  edge_msg4<<<EG4, 512, 0, stream>>>(FG, m_buf, ep, wfb + 81920 + 16384,
                                     msbh + 256, msbout + 128);
  // final aggregation
  seg_agg2<<<(K_N_ATOMS * 8 + 255) / 256, 256, 0, stream>>>(m_buf, start, stb);

  // readout
  mol_sum2<<<(K_N_MOLS * 8 + 255) / 256, 256, 0, stream>>>(stb, mstart, mol);
  mlp_layer8<64><<<K_N_MOLS / 8, 256, 0, stream>>>(mol, roWin, robin, r1);
  mlp_layer8<256><<<K_N_MOLS / 8, 256, 0, stream>>>(r1, roWh, robh, r2);
  mlp_layer8<256><<<K_N_MOLS / 8, 256, 0, stream>>>(r2, roWh + 256 * 256, robh + 256, r1);
  mlp_out_k<<<K_N_MOLS / 4, 256, 0, stream>>>(r1, roWout, robout, out);
}